// Round 11
// baseline (440.186 us; speedup 1.0000x reference)
//
#include <hip/hip_runtime.h>
#include <hip/hip_fp16.h>

// ---------------------------------------------------------------------------
// 3-layer GAT (heads=1) forward. N=100000, E=1600000, Ep=E+N, G=128,
// ND=16, ED=2, H=32.
// R11: incremental readout. R10 lesson: the LAST-fused epilogue re-reading
// x1/x2 (25MB) inside the 1.2TB/s gather kernel cost +30us -- worse than the
// k_dot it replaced. Now EVERY layer's agg epilogue dots its own res with its
// W_l3 slice (in-register, 32 fma + 5 shfl + 1 atomic/node) into gsum.
// No x-re-read anywhere; layer-2 skips the xout store (x3 never hits memory).
// Carried: 32-lane agg groups (R8 body), fp16 h (R8), NT rec loads (R7),
// LDS bucket sort (R6), k_pre/k_mid consolidation (R9).
// ---------------------------------------------------------------------------

#define NBUCK_SHIFT 8
#define NBUCK_MAX 512
#define CAP 6144   // max staged edges per 256-node bucket (mean ~4350, max ~4650)

// ---- fused preprocessing: [node_enc | colsum | hist | bounds] -------------
__global__ void k_pre(const float* __restrict__ nf, const float* __restrict__ Wne,
                      const float* __restrict__ bne, float* __restrict__ x0,
                      const float4* __restrict__ ea4, const float* __restrict__ Wee,
                      const float* __restrict__ bee, float2* __restrict__ partial,
                      const int* __restrict__ ei1, int* __restrict__ bucket_cnt,
                      const int* __restrict__ batch, int* __restrict__ bounds,
                      int n, int e, int ep, int nbNE, int nbCS, int nbH) {
    int b = blockIdx.x, t = threadIdx.x;
    if (b < nbNE) {
        int gid = b * 256 + t;
        if (gid >= n * 16) return;
        int node = gid >> 4, j = gid & 15;
        const float* xr = nf + node * 9;
        float acc = bne[j];
#pragma unroll
        for (int k = 0; k < 9; ++k) acc += xr[k] * Wne[k * 16 + j];
        x0[gid] = acc;
        return;
    }
    b -= nbNE;
    if (b < nbCS) {
        int tid = b * 256 + t;
        int e4 = e >> 2;
        float s0 = 0.f, s1 = 0.f;
        if (tid < e4) {
            float4 q0 = ea4[tid * 3], q1 = ea4[tid * 3 + 1], q2 = ea4[tid * 3 + 2];
            float a = q0.x + q0.w + q1.z + q2.y;
            float b2 = q0.y + q1.x + q1.w + q2.z;
            float c = q0.z + q1.y + q2.x + q2.w;
            s0 = a * Wee[0] + b2 * Wee[2] + c * Wee[4] + 4.f * bee[0];
            s1 = a * Wee[1] + b2 * Wee[3] + c * Wee[5] + 4.f * bee[1];
        }
#pragma unroll
        for (int off = 32; off > 0; off >>= 1) {
            s0 += __shfl_xor(s0, off, 64);
            s1 += __shfl_xor(s1, off, 64);
        }
        if ((t & 63) == 0)
            partial[(b << 2) + (t >> 6)] = make_float2(s0, s1);
        return;
    }
    b -= nbCS;
    if (b < nbH) {
        __shared__ int lh[NBUCK_MAX];
        lh[t] = 0; lh[t + 256] = 0;
        __syncthreads();
        int base = b * 4096;
#pragma unroll
        for (int i = 0; i < 16; ++i) {
            int gid = base + i * 256 + t;
            if (gid < ep) {
                int d = (gid < e) ? ei1[gid] : gid - e;
                atomicAdd(&lh[d >> NBUCK_SHIFT], 1);
            }
        }
        __syncthreads();
        if (lh[t]) atomicAdd(&bucket_cnt[t], lh[t]);
        if (lh[t + 256]) atomicAdd(&bucket_cnt[t + 256], lh[t + 256]);
        return;
    }
    for (int g = t; g <= 128; g += 256) {
        if (g == 128) { bounds[128] = n; continue; }
        int lo = 0, hi = n;
        while (lo < hi) {
            int mid = (lo + hi) >> 1;
            if (batch[mid] < g) lo = mid + 1; else hi = mid;
        }
        bounds[g] = lo;
    }
}

// ---- fused mid: block 0 = consts reduce, block 1 = bucket-base scan -------
__global__ void __launch_bounds__(512)
k_mid(const float* __restrict__ We0, const float* __restrict__ ae0,
      const float* __restrict__ We1, const float* __restrict__ ae1,
      const float* __restrict__ We2, const float* __restrict__ ae2,
      const float2* __restrict__ partial, int nw, float einv,
      float* __restrict__ consts,
      const int* __restrict__ bucket_cnt, int* __restrict__ bucket_base,
      int* __restrict__ bcursor, int nbuck, int ep, int* __restrict__ rp, int n) {
    int t = threadIdx.x;
    if (blockIdx.x == 0) {
        __shared__ float r0[512], r1[512];
        float m0 = 0.f, m1 = 0.f;
        for (int i = t; i < nw; i += 512) {
            float2 v = partial[i];
            m0 += v.x; m1 += v.y;
        }
        r0[t] = m0; r1[t] = m1;
        __syncthreads();
        for (int o = 256; o > 0; o >>= 1) {
            if (t < o) { r0[t] += r0[t + o]; r1[t] += r1[t + o]; }
            __syncthreads();
        }
        if (t == 0) {
            consts[12] = r0[0] * einv;
            consts[13] = r1[0] * einv;
            const float* We[3] = {We0, We1, We2};
            const float* ae[3] = {ae0, ae1, ae2};
            for (int l = 0; l < 3; ++l) {
                float c0 = 0.f, c1 = 0.f;
                for (int j = 0; j < 32; ++j) {
                    c0 += We[l][j] * ae[l][j];
                    c1 += We[l][32 + j] * ae[l][j];
                }
                consts[l * 2 + 0] = c0;
                consts[l * 2 + 1] = c1;
            }
        }
    } else {
        __shared__ int s[512];
        int v = (t < nbuck) ? bucket_cnt[t] : 0;
        s[t] = v;
        __syncthreads();
        for (int o = 1; o < 512; o <<= 1) {
            int x = (t >= o) ? s[t - o] : 0;
            __syncthreads();
            s[t] += x;
            __syncthreads();
        }
        int ex = s[t] - v;
        if (t < nbuck) { bucket_base[t] = ex; bcursor[t] = ex; }
        if (t == 0) { bucket_base[nbuck] = ep; rp[n] = ep; }
    }
}

// Phase B: stage edges grouped by bucket; one 8B uint2 {src<<8|dloc, half2}
// per edge; per-(block,bucket) run reservation keeps stores line-local.
__global__ void k_binB(const int* __restrict__ ei0, const int* __restrict__ ei1,
                       const float* __restrict__ ea, const float* __restrict__ We,
                       const float* __restrict__ be, const float* __restrict__ consts,
                       int* __restrict__ bcursor, uint2* __restrict__ st, int e, int ep) {
    __shared__ int lh[NBUCK_MAX], lcur[NBUCK_MAX];
    int t = threadIdx.x;
    lh[t] = 0; lh[t + 256] = 0;
    __syncthreads();
    int base = blockIdx.x * 4096;
    unsigned int sd[16], fh[16];
    int bk[16];
    float w00 = We[0], w10 = We[2], w20 = We[4];
    float w01 = We[1], w11 = We[3], w21 = We[5];
    float b0 = be[0], b1 = be[1];
#pragma unroll
    for (int i = 0; i < 16; ++i) {
        int gid = base + i * 256 + t;
        bk[i] = -1;
        if (gid < ep) {
            int s, d; float f0, f1;
            if (gid < e) {
                s = ei0[gid]; d = ei1[gid];
                const float* r = ea + (size_t)gid * 3;
                float a0 = r[0], a1 = r[1], a2 = r[2];
                f0 = a0 * w00 + a1 * w10 + a2 * w20 + b0;
                f1 = a0 * w01 + a1 * w11 + a2 * w21 + b1;
            } else {
                s = d = gid - e;
                f0 = consts[12]; f1 = consts[13];
            }
            bk[i] = d >> NBUCK_SHIFT;
            sd[i] = ((unsigned int)s << NBUCK_SHIFT) | (unsigned int)(d & 255);
            __half2 hh = __floats2half2_rn(f0, f1);
            fh[i] = *reinterpret_cast<unsigned int*>(&hh);
            atomicAdd(&lh[bk[i]], 1);
        }
    }
    __syncthreads();
    if (lh[t] > 0) lcur[t] = atomicAdd(&bcursor[t], lh[t]);
    if (lh[t + 256] > 0) lcur[t + 256] = atomicAdd(&bcursor[t + 256], lh[t + 256]);
    __syncthreads();
#pragma unroll
    for (int i = 0; i < 16; ++i) {
        if (bk[i] >= 0) {
            int pos = atomicAdd(&lcur[bk[i]], 1);
            st[pos] = make_uint2(sd[i], fh[i]);
        }
    }
}

// Phase C: one 512-thread block per bucket. LDS node-hist + scan -> rp
// coalesced; scatter into LDS-sorted buffer; stream out coalesced.
__global__ void __launch_bounds__(512)
k_binC(const uint2* __restrict__ st, const int* __restrict__ bucket_base,
       int* __restrict__ rp, uint2* __restrict__ rec, int n) {
    __shared__ int nh[256], ns[256];
    __shared__ uint2 rs[CAP];
    int k = blockIdx.x, t = threadIdx.x;
    int s0 = bucket_base[k], s1 = bucket_base[k + 1];
    int cnt = s1 - s0;
    if (t < 256) nh[t] = 0;
    __syncthreads();
    for (int i = s0 + t; i < s1; i += 512)
        atomicAdd(&nh[st[i].x & 255], 1);
    __syncthreads();
    if (t < 256) ns[t] = nh[t];
    __syncthreads();
    for (int o = 1; o < 256; o <<= 1) {
        int add = 0;
        if (t < 256 && t >= o) add = ns[t - o];
        __syncthreads();
        if (t < 256) ns[t] += add;
        __syncthreads();
    }
    int node0 = k << NBUCK_SHIFT;
    if (t < 256) {
        int startl = ns[t] - nh[t];      // exclusive, bucket-local
        if (node0 + t < n) rp[node0 + t] = s0 + startl;
        nh[t] = startl;                  // becomes local cursor
    }
    __syncthreads();
    for (int i = s0 + t; i < s1; i += 512) {
        uint2 v = st[i];
        int pos = atomicAdd(&nh[v.x & 255], 1);
        uint2 r = make_uint2(v.x >> NBUCK_SHIFT, v.y);
        if (pos < CAP) rs[pos] = r;
        else rec[s0 + pos] = r;          // overflow fallback (never in practice)
    }
    __syncthreads();
    int m = cnt < CAP ? cnt : CAP;
    for (int i = t; i < m; i += 512)
        rec[s0 + i] = rs[i];
}

// h stored packed half2: h2[node*16 + (j>>1)] holds cols (2k, 2k+1).
template <int K>
__global__ void k_hproj(const float* __restrict__ x, const float* __restrict__ W,
                        const float* __restrict__ as_, const float* __restrict__ ad_,
                        unsigned int* __restrict__ h2, float* __restrict__ asrc,
                        float* __restrict__ adst, int n) {
    __shared__ float sW[K * 32];
    for (int i = threadIdx.x; i < K * 32; i += 256) sW[i] = W[i];
    __syncthreads();
    int node = blockIdx.x * 8 + (threadIdx.x >> 5);
    int j = threadIdx.x & 31;
    if (node >= n) return;
    const float* xr = x + (size_t)node * K;
    float acc = 0.f;
#pragma unroll
    for (int k = 0; k < K; ++k) acc += xr[k] * sW[k * 32 + j];
    float accp = __shfl_down(acc, 1, 32);
    if ((j & 1) == 0) {
        __half2 hh = __floats2half2_rn(acc, accp);
        h2[(size_t)node * 16 + (j >> 1)] = *reinterpret_cast<unsigned int*>(&hh);
    }
    float r1 = acc * as_[j], r2 = acc * ad_[j];
    for (int off = 16; off > 0; off >>= 1) {
        r1 += __shfl_xor(r1, off, 32);
        r2 += __shfl_xor(r2, off, 32);
    }
    if (j == 0) { asrc[node] = r1; adst[node] = r2; }
}

__device__ __forceinline__ float h2_get(const unsigned int* __restrict__ h2,
                                        int s, int word, bool hi) {
    unsigned int hw = h2[(size_t)s * 16 + word];
    __half2 hh = *reinterpret_cast<__half2*>(&hw);
    return hi ? __high2float(hh) : __low2float(hh);
}

// Fused edge-softmax + aggregation, 32-lane group per dst node (R8 body).
// Epilogue: incremental readout -- res . Wl3-slice reduced in-register,
// one atomic per node into gsum. STORE=false (last layer) skips xout.
template <bool STORE>
__global__ void k_agg(const int* __restrict__ rp, const uint2* __restrict__ rec,
                      const float* __restrict__ asrc, const float* __restrict__ adst,
                      const float* __restrict__ consts, const unsigned int* __restrict__ h2,
                      const float* __restrict__ bb, float* __restrict__ xout,
                      const int* __restrict__ batch, const float* __restrict__ wl3,
                      float* __restrict__ gsum, int n, int layer) {
    int node = blockIdx.x * 8 + (threadIdx.x >> 5);
    int j = threadIdx.x & 31;
    if (node >= n) return;
    float c0 = consts[layer * 2], c1 = consts[layer * 2 + 1];
    int r0 = rp[node], r1 = rp[node + 1];
    float adn = adst[node];
    int word = j >> 1;
    bool hi = (j & 1) != 0;
    float acc = 0.f, psum = 0.f;
    for (int c = r0; c < r1; c += 32) {
        int i = c + j;
        float pe = 0.f; int s = 0;
        if (i < r1) {
            unsigned long long rv = __builtin_nontemporal_load(
                reinterpret_cast<const unsigned long long*>(rec + i));
            s = (int)(unsigned int)(rv & 0xffffffffull);
            unsigned int fv = (unsigned int)(rv >> 32);
            __half2 hh = *reinterpret_cast<__half2*>(&fv);
            float lg = asrc[s] + adn + __low2float(hh) * c0 + __high2float(hh) * c1;
            lg = lg > 0.f ? lg : 0.2f * lg;
            pe = __expf(lg);
        }
        psum += pe;
        int cnt = min(32, r1 - c);
        int t = 0;
        for (; t + 8 <= cnt; t += 8) {
            int s0 = __shfl(s, t, 32),     s1 = __shfl(s, t + 1, 32);
            int s2 = __shfl(s, t + 2, 32), s3 = __shfl(s, t + 3, 32);
            int s4 = __shfl(s, t + 4, 32), s5 = __shfl(s, t + 5, 32);
            int s6 = __shfl(s, t + 6, 32), s7 = __shfl(s, t + 7, 32);
            float p0 = __shfl(pe, t, 32),     p1 = __shfl(pe, t + 1, 32);
            float p2 = __shfl(pe, t + 2, 32), p3 = __shfl(pe, t + 3, 32);
            float p4 = __shfl(pe, t + 4, 32), p5 = __shfl(pe, t + 5, 32);
            float p6 = __shfl(pe, t + 6, 32), p7 = __shfl(pe, t + 7, 32);
            float h0 = h2_get(h2, s0, word, hi);
            float h1 = h2_get(h2, s1, word, hi);
            float h2v = h2_get(h2, s2, word, hi);
            float h3 = h2_get(h2, s3, word, hi);
            float h4 = h2_get(h2, s4, word, hi);
            float h5 = h2_get(h2, s5, word, hi);
            float h6 = h2_get(h2, s6, word, hi);
            float h7 = h2_get(h2, s7, word, hi);
            acc += p0 * h0; acc += p1 * h1; acc += p2 * h2v; acc += p3 * h3;
            acc += p4 * h4; acc += p5 * h5; acc += p6 * h6; acc += p7 * h7;
        }
        for (; t + 4 <= cnt; t += 4) {
            int s0 = __shfl(s, t, 32),     s1 = __shfl(s, t + 1, 32);
            int s2 = __shfl(s, t + 2, 32), s3 = __shfl(s, t + 3, 32);
            float p0 = __shfl(pe, t, 32),     p1 = __shfl(pe, t + 1, 32);
            float p2 = __shfl(pe, t + 2, 32), p3 = __shfl(pe, t + 3, 32);
            float h0 = h2_get(h2, s0, word, hi);
            float h1 = h2_get(h2, s1, word, hi);
            float h2v = h2_get(h2, s2, word, hi);
            float h3 = h2_get(h2, s3, word, hi);
            acc += p0 * h0; acc += p1 * h1; acc += p2 * h2v; acc += p3 * h3;
        }
        for (; t < cnt; ++t) {
            int st2 = __shfl(s, t, 32);
            float pt = __shfl(pe, t, 32);
            acc += pt * h2_get(h2, st2, word, hi);
        }
    }
#pragma unroll
    for (int off = 16; off > 0; off >>= 1) psum += __shfl_xor(psum, off, 32);
    float res = acc / (psum + 1e-16f) + bb[j];
    if (STORE) xout[(size_t)node * 32 + j] = res;
    // incremental readout: this layer's contribution to pooled @ W_l3
    float v = res * wl3[j];
#pragma unroll
    for (int off = 16; off > 0; off >>= 1) v += __shfl_xor(v, off, 32);
    if (j == 0) atomicAdd(gsum + (size_t)batch[node] * 32 + (blockIdx.x & 31), v);
}

__global__ void k_out(const float* __restrict__ gsum, const int* __restrict__ bounds,
                      const float* __restrict__ bl3, float* __restrict__ out, int g) {
    int t = threadIdx.x;
    if (t >= g) return;
    float acc = 0.f;
    for (int k = 0; k < 32; ++k) acc += gsum[(size_t)t * 32 + k];
    float cnt = (float)(bounds[t + 1] - bounds[t]);
    out[t] = acc / fmaxf(cnt, 1.f) + bl3[0];
}

extern "C" void kernel_launch(void* const* d_in, const int* in_sizes, int n_in,
                              void* d_out, int out_size, void* d_ws, size_t ws_size,
                              hipStream_t stream) {
    (void)n_in; (void)out_size; (void)ws_size;
    const float* nf    = (const float*)d_in[0];
    const int*   ei    = (const int*)d_in[1];
    const float* ea    = (const float*)d_in[2];
    const int*   batch = (const int*)d_in[3];
    const float* W_ne  = (const float*)d_in[4];
    const float* b_ne  = (const float*)d_in[5];
    const float* W_ee  = (const float*)d_in[6];
    const float* b_ee  = (const float*)d_in[7];
    const float* W_l3  = (const float*)d_in[8];
    const float* b_l3  = (const float*)d_in[9];
    const float *Wl[3], *asl[3], *adl[3], *Wel[3], *ael[3], *bbl[3];
    for (int l = 0; l < 3; ++l) {
        Wl[l]  = (const float*)d_in[10 + 6 * l];
        asl[l] = (const float*)d_in[11 + 6 * l];
        adl[l] = (const float*)d_in[12 + 6 * l];
        Wel[l] = (const float*)d_in[13 + 6 * l];
        ael[l] = (const float*)d_in[14 + 6 * l];
        bbl[l] = (const float*)d_in[15 + 6 * l];
    }

    const int n  = in_sizes[3];        // 100000
    const int e  = in_sizes[2] / 3;    // 1600000
    const int ep = e + n;
    const int* ei0 = ei;
    const int* ei1 = ei + e;
    const int nbuck = (n + 255) >> NBUCK_SHIFT;   // 391

    char* w = (char*)d_ws;
    size_t off = 0;
    auto alloc = [&](size_t b) { size_t o = off; off = (off + b + 255) & ~(size_t)255; return o; };
    float*        x0      = (float*)(w + alloc((size_t)n * 16 * 4));
    float*        x1      = (float*)(w + alloc((size_t)n * 32 * 4));
    float*        x2      = (float*)(w + alloc((size_t)n * 32 * 4));
    unsigned int* h2      = (unsigned int*)(w + alloc((size_t)n * 16 * 4));
    float*        asrc    = (float*)(w + alloc((size_t)n * 4));
    float*        adst    = (float*)(w + alloc((size_t)n * 4));
    uint2*        st      = (uint2*)(w + alloc((size_t)ep * 8));
    uint2*        rec     = (uint2*)(w + alloc((size_t)ep * 8));
    int*          rp      = (int*)(w + alloc((size_t)(n + 1) * 4));
    int*          bcnt    = (int*)(w + alloc(NBUCK_MAX * 4));
    int*          bbase   = (int*)(w + alloc((NBUCK_MAX + 1) * 4));
    int*          bcur    = (int*)(w + alloc(NBUCK_MAX * 4));
    float2*       partial = (float2*)(w + alloc((size_t)8192 * 8));
    float*        consts  = (float*)(w + alloc(256));
    int*          bounds  = (int*)(w + alloc(129 * 4));
    float*        gsum    = (float*)(w + alloc((size_t)128 * 32 * 4));

    hipMemsetAsync(bcnt, 0, NBUCK_MAX * 4, stream);
    hipMemsetAsync(gsum, 0, (size_t)128 * 32 * 4, stream);

    int e4   = e >> 2;
    int nbNE = (n * 16 + 255) / 256;     // 6250
    int nbCS = (e4 + 255) / 256;         // 1563
    int nbH  = (ep + 4095) / 4096;       // 416
    int nw   = nbCS * 4;

    k_pre<<<nbNE + nbCS + nbH + 1, 256, 0, stream>>>(
        nf, W_ne, b_ne, x0, (const float4*)ea, W_ee, b_ee, partial,
        ei1, bcnt, batch, bounds, n, e, ep, nbNE, nbCS, nbH);
    k_mid<<<2, 512, 0, stream>>>(Wel[0], ael[0], Wel[1], ael[1], Wel[2], ael[2],
                                 partial, nw, 1.0f / (float)e, consts,
                                 bcnt, bbase, bcur, nbuck, ep, rp, n);
    k_binB<<<nbH, 256, 0, stream>>>(ei0, ei1, ea, W_ee, b_ee, consts, bcur, st, e, ep);
    k_binC<<<nbuck, 512, 0, stream>>>(st, bbase, rp, rec, n);

    const float* xin = x0;
    float* xo[2] = {x1, x2};
    for (int l = 0; l < 3; ++l) {
        if (l == 0)
            k_hproj<16><<<(n + 7) / 8, 256, 0, stream>>>(xin, Wl[l], asl[l], adl[l],
                                                         h2, asrc, adst, n);
        else
            k_hproj<32><<<(n + 7) / 8, 256, 0, stream>>>(xin, Wl[l], asl[l], adl[l],
                                                         h2, asrc, adst, n);
        if (l < 2) {
            k_agg<true><<<(n + 7) / 8, 256, 0, stream>>>(
                rp, rec, asrc, adst, consts, h2, bbl[l], xo[l],
                batch, W_l3 + 32 * l, gsum, n, l);
            xin = xo[l];
        } else {
            k_agg<false><<<(n + 7) / 8, 256, 0, stream>>>(
                rp, rec, asrc, adst, consts, h2, bbl[l], nullptr,
                batch, W_l3 + 32 * l, gsum, n, l);
        }
    }
    k_out<<<1, 128, 0, stream>>>(gsum, bounds, b_l3, (float*)d_out, 128);
}

// Round 12
// 382.283 us; speedup vs baseline: 1.1515x; 1.1515x over previous
//
#include <hip/hip_runtime.h>
#include <hip/hip_fp16.h>

// ---------------------------------------------------------------------------
// 3-layer GAT (heads=1) forward. N=100000, E=1600000, Ep=E+N, G=128,
// ND=16, ED=2, H=32.
// R12: atomic-free readout. R9-R11 lesson: a per-node gsum atomicAdd costs
// ~+29us in whatever kernel hosts it (sorted batch -> ~780 same-line RMWs
// burst at one L2 slice). All k_agg reverted to the clean R8 body (plain
// xout store, 41us); readout = k_dot3, one block/graph, coalesced float2
// strided loads + LDS tree reduce, writes out[g] directly. No atomics.
// Carried: 32-lane agg groups + fp16 h (R8), NT rec loads (R7), LDS bucket
// sort (R6), k_pre/k_mid consolidation (R9).
// ---------------------------------------------------------------------------

#define NBUCK_SHIFT 8
#define NBUCK_MAX 512
#define CAP 6144   // max staged edges per 256-node bucket (mean ~4350, max ~4650)

// ---- fused preprocessing: [node_enc | colsum | hist | bounds] -------------
__global__ void k_pre(const float* __restrict__ nf, const float* __restrict__ Wne,
                      const float* __restrict__ bne, float* __restrict__ x0,
                      const float4* __restrict__ ea4, const float* __restrict__ Wee,
                      const float* __restrict__ bee, float2* __restrict__ partial,
                      const int* __restrict__ ei1, int* __restrict__ bucket_cnt,
                      const int* __restrict__ batch, int* __restrict__ bounds,
                      int n, int e, int ep, int nbNE, int nbCS, int nbH) {
    int b = blockIdx.x, t = threadIdx.x;
    if (b < nbNE) {
        int gid = b * 256 + t;
        if (gid >= n * 16) return;
        int node = gid >> 4, j = gid & 15;
        const float* xr = nf + node * 9;
        float acc = bne[j];
#pragma unroll
        for (int k = 0; k < 9; ++k) acc += xr[k] * Wne[k * 16 + j];
        x0[gid] = acc;
        return;
    }
    b -= nbNE;
    if (b < nbCS) {
        int tid = b * 256 + t;
        int e4 = e >> 2;
        float s0 = 0.f, s1 = 0.f;
        if (tid < e4) {
            float4 q0 = ea4[tid * 3], q1 = ea4[tid * 3 + 1], q2 = ea4[tid * 3 + 2];
            float a = q0.x + q0.w + q1.z + q2.y;
            float b2 = q0.y + q1.x + q1.w + q2.z;
            float c = q0.z + q1.y + q2.x + q2.w;
            s0 = a * Wee[0] + b2 * Wee[2] + c * Wee[4] + 4.f * bee[0];
            s1 = a * Wee[1] + b2 * Wee[3] + c * Wee[5] + 4.f * bee[1];
        }
#pragma unroll
        for (int off = 32; off > 0; off >>= 1) {
            s0 += __shfl_xor(s0, off, 64);
            s1 += __shfl_xor(s1, off, 64);
        }
        if ((t & 63) == 0)
            partial[(b << 2) + (t >> 6)] = make_float2(s0, s1);
        return;
    }
    b -= nbCS;
    if (b < nbH) {
        __shared__ int lh[NBUCK_MAX];
        lh[t] = 0; lh[t + 256] = 0;
        __syncthreads();
        int base = b * 4096;
#pragma unroll
        for (int i = 0; i < 16; ++i) {
            int gid = base + i * 256 + t;
            if (gid < ep) {
                int d = (gid < e) ? ei1[gid] : gid - e;
                atomicAdd(&lh[d >> NBUCK_SHIFT], 1);
            }
        }
        __syncthreads();
        if (lh[t]) atomicAdd(&bucket_cnt[t], lh[t]);
        if (lh[t + 256]) atomicAdd(&bucket_cnt[t + 256], lh[t + 256]);
        return;
    }
    for (int g = t; g <= 128; g += 256) {
        if (g == 128) { bounds[128] = n; continue; }
        int lo = 0, hi = n;
        while (lo < hi) {
            int mid = (lo + hi) >> 1;
            if (batch[mid] < g) lo = mid + 1; else hi = mid;
        }
        bounds[g] = lo;
    }
}

// ---- fused mid: block 0 = consts reduce, block 1 = bucket-base scan -------
__global__ void __launch_bounds__(512)
k_mid(const float* __restrict__ We0, const float* __restrict__ ae0,
      const float* __restrict__ We1, const float* __restrict__ ae1,
      const float* __restrict__ We2, const float* __restrict__ ae2,
      const float2* __restrict__ partial, int nw, float einv,
      float* __restrict__ consts,
      const int* __restrict__ bucket_cnt, int* __restrict__ bucket_base,
      int* __restrict__ bcursor, int nbuck, int ep, int* __restrict__ rp, int n) {
    int t = threadIdx.x;
    if (blockIdx.x == 0) {
        __shared__ float r0[512], r1[512];
        float m0 = 0.f, m1 = 0.f;
        for (int i = t; i < nw; i += 512) {
            float2 v = partial[i];
            m0 += v.x; m1 += v.y;
        }
        r0[t] = m0; r1[t] = m1;
        __syncthreads();
        for (int o = 256; o > 0; o >>= 1) {
            if (t < o) { r0[t] += r0[t + o]; r1[t] += r1[t + o]; }
            __syncthreads();
        }
        if (t == 0) {
            consts[12] = r0[0] * einv;
            consts[13] = r1[0] * einv;
            const float* We[3] = {We0, We1, We2};
            const float* ae[3] = {ae0, ae1, ae2};
            for (int l = 0; l < 3; ++l) {
                float c0 = 0.f, c1 = 0.f;
                for (int j = 0; j < 32; ++j) {
                    c0 += We[l][j] * ae[l][j];
                    c1 += We[l][32 + j] * ae[l][j];
                }
                consts[l * 2 + 0] = c0;
                consts[l * 2 + 1] = c1;
            }
        }
    } else {
        __shared__ int s[512];
        int v = (t < nbuck) ? bucket_cnt[t] : 0;
        s[t] = v;
        __syncthreads();
        for (int o = 1; o < 512; o <<= 1) {
            int x = (t >= o) ? s[t - o] : 0;
            __syncthreads();
            s[t] += x;
            __syncthreads();
        }
        int ex = s[t] - v;
        if (t < nbuck) { bucket_base[t] = ex; bcursor[t] = ex; }
        if (t == 0) { bucket_base[nbuck] = ep; rp[n] = ep; }
    }
}

// Phase B: stage edges grouped by bucket; one 8B uint2 {src<<8|dloc, half2}
// per edge; per-(block,bucket) run reservation keeps stores line-local.
__global__ void k_binB(const int* __restrict__ ei0, const int* __restrict__ ei1,
                       const float* __restrict__ ea, const float* __restrict__ We,
                       const float* __restrict__ be, const float* __restrict__ consts,
                       int* __restrict__ bcursor, uint2* __restrict__ st, int e, int ep) {
    __shared__ int lh[NBUCK_MAX], lcur[NBUCK_MAX];
    int t = threadIdx.x;
    lh[t] = 0; lh[t + 256] = 0;
    __syncthreads();
    int base = blockIdx.x * 4096;
    unsigned int sd[16], fh[16];
    int bk[16];
    float w00 = We[0], w10 = We[2], w20 = We[4];
    float w01 = We[1], w11 = We[3], w21 = We[5];
    float b0 = be[0], b1 = be[1];
#pragma unroll
    for (int i = 0; i < 16; ++i) {
        int gid = base + i * 256 + t;
        bk[i] = -1;
        if (gid < ep) {
            int s, d; float f0, f1;
            if (gid < e) {
                s = ei0[gid]; d = ei1[gid];
                const float* r = ea + (size_t)gid * 3;
                float a0 = r[0], a1 = r[1], a2 = r[2];
                f0 = a0 * w00 + a1 * w10 + a2 * w20 + b0;
                f1 = a0 * w01 + a1 * w11 + a2 * w21 + b1;
            } else {
                s = d = gid - e;
                f0 = consts[12]; f1 = consts[13];
            }
            bk[i] = d >> NBUCK_SHIFT;
            sd[i] = ((unsigned int)s << NBUCK_SHIFT) | (unsigned int)(d & 255);
            __half2 hh = __floats2half2_rn(f0, f1);
            fh[i] = *reinterpret_cast<unsigned int*>(&hh);
            atomicAdd(&lh[bk[i]], 1);
        }
    }
    __syncthreads();
    if (lh[t] > 0) lcur[t] = atomicAdd(&bcursor[t], lh[t]);
    if (lh[t + 256] > 0) lcur[t + 256] = atomicAdd(&bcursor[t + 256], lh[t + 256]);
    __syncthreads();
#pragma unroll
    for (int i = 0; i < 16; ++i) {
        if (bk[i] >= 0) {
            int pos = atomicAdd(&lcur[bk[i]], 1);
            st[pos] = make_uint2(sd[i], fh[i]);
        }
    }
}

// Phase C: one 512-thread block per bucket. LDS node-hist + scan -> rp
// coalesced; scatter into LDS-sorted buffer; stream out coalesced.
__global__ void __launch_bounds__(512)
k_binC(const uint2* __restrict__ st, const int* __restrict__ bucket_base,
       int* __restrict__ rp, uint2* __restrict__ rec, int n) {
    __shared__ int nh[256], ns[256];
    __shared__ uint2 rs[CAP];
    int k = blockIdx.x, t = threadIdx.x;
    int s0 = bucket_base[k], s1 = bucket_base[k + 1];
    int cnt = s1 - s0;
    if (t < 256) nh[t] = 0;
    __syncthreads();
    for (int i = s0 + t; i < s1; i += 512)
        atomicAdd(&nh[st[i].x & 255], 1);
    __syncthreads();
    if (t < 256) ns[t] = nh[t];
    __syncthreads();
    for (int o = 1; o < 256; o <<= 1) {
        int add = 0;
        if (t < 256 && t >= o) add = ns[t - o];
        __syncthreads();
        if (t < 256) ns[t] += add;
        __syncthreads();
    }
    int node0 = k << NBUCK_SHIFT;
    if (t < 256) {
        int startl = ns[t] - nh[t];      // exclusive, bucket-local
        if (node0 + t < n) rp[node0 + t] = s0 + startl;
        nh[t] = startl;                  // becomes local cursor
    }
    __syncthreads();
    for (int i = s0 + t; i < s1; i += 512) {
        uint2 v = st[i];
        int pos = atomicAdd(&nh[v.x & 255], 1);
        uint2 r = make_uint2(v.x >> NBUCK_SHIFT, v.y);
        if (pos < CAP) rs[pos] = r;
        else rec[s0 + pos] = r;          // overflow fallback (never in practice)
    }
    __syncthreads();
    int m = cnt < CAP ? cnt : CAP;
    for (int i = t; i < m; i += 512)
        rec[s0 + i] = rs[i];
}

// h stored packed half2: h2[node*16 + (j>>1)] holds cols (2k, 2k+1).
template <int K>
__global__ void k_hproj(const float* __restrict__ x, const float* __restrict__ W,
                        const float* __restrict__ as_, const float* __restrict__ ad_,
                        unsigned int* __restrict__ h2, float* __restrict__ asrc,
                        float* __restrict__ adst, int n) {
    __shared__ float sW[K * 32];
    for (int i = threadIdx.x; i < K * 32; i += 256) sW[i] = W[i];
    __syncthreads();
    int node = blockIdx.x * 8 + (threadIdx.x >> 5);
    int j = threadIdx.x & 31;
    if (node >= n) return;
    const float* xr = x + (size_t)node * K;
    float acc = 0.f;
#pragma unroll
    for (int k = 0; k < K; ++k) acc += xr[k] * sW[k * 32 + j];
    float accp = __shfl_down(acc, 1, 32);
    if ((j & 1) == 0) {
        __half2 hh = __floats2half2_rn(acc, accp);
        h2[(size_t)node * 16 + (j >> 1)] = *reinterpret_cast<unsigned int*>(&hh);
    }
    float r1 = acc * as_[j], r2 = acc * ad_[j];
    for (int off = 16; off > 0; off >>= 1) {
        r1 += __shfl_xor(r1, off, 32);
        r2 += __shfl_xor(r2, off, 32);
    }
    if (j == 0) { asrc[node] = r1; adst[node] = r2; }
}

__device__ __forceinline__ float h2_get(const unsigned int* __restrict__ h2,
                                        int s, int word, bool hi) {
    unsigned int hw = h2[(size_t)s * 16 + word];
    __half2 hh = *reinterpret_cast<__half2*>(&hw);
    return hi ? __high2float(hh) : __low2float(hh);
}

// Fused edge-softmax + aggregation, 32-lane group per dst node (R8 body).
// No epilogue beyond the xout store -- atomics are banned here (R11 lesson).
__global__ void k_agg(const int* __restrict__ rp, const uint2* __restrict__ rec,
                      const float* __restrict__ asrc, const float* __restrict__ adst,
                      const float* __restrict__ consts, const unsigned int* __restrict__ h2,
                      const float* __restrict__ bb, float* __restrict__ xout,
                      int n, int layer) {
    int node = blockIdx.x * 8 + (threadIdx.x >> 5);
    int j = threadIdx.x & 31;
    if (node >= n) return;
    float c0 = consts[layer * 2], c1 = consts[layer * 2 + 1];
    int r0 = rp[node], r1 = rp[node + 1];
    float adn = adst[node];
    int word = j >> 1;
    bool hi = (j & 1) != 0;
    float acc = 0.f, psum = 0.f;
    for (int c = r0; c < r1; c += 32) {
        int i = c + j;
        float pe = 0.f; int s = 0;
        if (i < r1) {
            unsigned long long rv = __builtin_nontemporal_load(
                reinterpret_cast<const unsigned long long*>(rec + i));
            s = (int)(unsigned int)(rv & 0xffffffffull);
            unsigned int fv = (unsigned int)(rv >> 32);
            __half2 hh = *reinterpret_cast<__half2*>(&fv);
            float lg = asrc[s] + adn + __low2float(hh) * c0 + __high2float(hh) * c1;
            lg = lg > 0.f ? lg : 0.2f * lg;
            pe = __expf(lg);
        }
        psum += pe;
        int cnt = min(32, r1 - c);
        int t = 0;
        for (; t + 8 <= cnt; t += 8) {
            int s0 = __shfl(s, t, 32),     s1 = __shfl(s, t + 1, 32);
            int s2 = __shfl(s, t + 2, 32), s3 = __shfl(s, t + 3, 32);
            int s4 = __shfl(s, t + 4, 32), s5 = __shfl(s, t + 5, 32);
            int s6 = __shfl(s, t + 6, 32), s7 = __shfl(s, t + 7, 32);
            float p0 = __shfl(pe, t, 32),     p1 = __shfl(pe, t + 1, 32);
            float p2 = __shfl(pe, t + 2, 32), p3 = __shfl(pe, t + 3, 32);
            float p4 = __shfl(pe, t + 4, 32), p5 = __shfl(pe, t + 5, 32);
            float p6 = __shfl(pe, t + 6, 32), p7 = __shfl(pe, t + 7, 32);
            float h0 = h2_get(h2, s0, word, hi);
            float h1 = h2_get(h2, s1, word, hi);
            float h2v = h2_get(h2, s2, word, hi);
            float h3 = h2_get(h2, s3, word, hi);
            float h4 = h2_get(h2, s4, word, hi);
            float h5 = h2_get(h2, s5, word, hi);
            float h6 = h2_get(h2, s6, word, hi);
            float h7 = h2_get(h2, s7, word, hi);
            acc += p0 * h0; acc += p1 * h1; acc += p2 * h2v; acc += p3 * h3;
            acc += p4 * h4; acc += p5 * h5; acc += p6 * h6; acc += p7 * h7;
        }
        for (; t + 4 <= cnt; t += 4) {
            int s0 = __shfl(s, t, 32),     s1 = __shfl(s, t + 1, 32);
            int s2 = __shfl(s, t + 2, 32), s3 = __shfl(s, t + 3, 32);
            float p0 = __shfl(pe, t, 32),     p1 = __shfl(pe, t + 1, 32);
            float p2 = __shfl(pe, t + 2, 32), p3 = __shfl(pe, t + 3, 32);
            float h0 = h2_get(h2, s0, word, hi);
            float h1 = h2_get(h2, s1, word, hi);
            float h2v = h2_get(h2, s2, word, hi);
            float h3 = h2_get(h2, s3, word, hi);
            acc += p0 * h0; acc += p1 * h1; acc += p2 * h2v; acc += p3 * h3;
        }
        for (; t < cnt; ++t) {
            int st2 = __shfl(s, t, 32);
            float pt = __shfl(pe, t, 32);
            acc += pt * h2_get(h2, st2, word, hi);
        }
    }
#pragma unroll
    for (int off = 16; off > 0; off >>= 1) psum += __shfl_xor(psum, off, 32);
    xout[(size_t)node * 32 + j] = acc / (psum + 1e-16f) + bb[j];
}

// Readout, atomic-free: one block per graph. Thread t has fixed word w=t&15
// (coalesced float2 rows of x1/x2/x3); strided over the graph's nodes;
// LDS tree reduce; out[g] written directly (absorbs old k_out).
__global__ void k_dot3(const float2* __restrict__ x1, const float2* __restrict__ x2,
                       const float2* __restrict__ x3, const int* __restrict__ bounds,
                       const float* __restrict__ Wl3, const float* __restrict__ bl3,
                       float* __restrict__ out) {
    __shared__ float red[256];
    int g = blockIdx.x, t = threadIdx.x;
    int s0 = bounds[g], s1 = bounds[g + 1];
    int cnt = s1 - s0;
    int w = t & 15;
    const float2* W2 = reinterpret_cast<const float2*>(Wl3);
    float2 w1 = W2[w], w2 = W2[16 + w], w3 = W2[32 + w];
    float v = 0.f;
    for (int i = t; i < cnt * 16; i += 256) {
        int node = s0 + (i >> 4);
        float2 a1 = x1[(size_t)node * 16 + w];
        float2 a2 = x2[(size_t)node * 16 + w];
        float2 a3 = x3[(size_t)node * 16 + w];
        v += a1.x * w1.x + a1.y * w1.y
           + a2.x * w2.x + a2.y * w2.y
           + a3.x * w3.x + a3.y * w3.y;
    }
    red[t] = v;
    __syncthreads();
    for (int o = 128; o > 0; o >>= 1) {
        if (t < o) red[t] += red[t + o];
        __syncthreads();
    }
    if (t == 0) {
        float c = (float)cnt;
        if (c < 1.f) c = 1.f;
        out[g] = red[0] / c + bl3[0];
    }
}

extern "C" void kernel_launch(void* const* d_in, const int* in_sizes, int n_in,
                              void* d_out, int out_size, void* d_ws, size_t ws_size,
                              hipStream_t stream) {
    (void)n_in; (void)out_size; (void)ws_size;
    const float* nf    = (const float*)d_in[0];
    const int*   ei    = (const int*)d_in[1];
    const float* ea    = (const float*)d_in[2];
    const int*   batch = (const int*)d_in[3];
    const float* W_ne  = (const float*)d_in[4];
    const float* b_ne  = (const float*)d_in[5];
    const float* W_ee  = (const float*)d_in[6];
    const float* b_ee  = (const float*)d_in[7];
    const float* W_l3  = (const float*)d_in[8];
    const float* b_l3  = (const float*)d_in[9];
    const float *Wl[3], *asl[3], *adl[3], *Wel[3], *ael[3], *bbl[3];
    for (int l = 0; l < 3; ++l) {
        Wl[l]  = (const float*)d_in[10 + 6 * l];
        asl[l] = (const float*)d_in[11 + 6 * l];
        adl[l] = (const float*)d_in[12 + 6 * l];
        Wel[l] = (const float*)d_in[13 + 6 * l];
        ael[l] = (const float*)d_in[14 + 6 * l];
        bbl[l] = (const float*)d_in[15 + 6 * l];
    }

    const int n  = in_sizes[3];        // 100000
    const int e  = in_sizes[2] / 3;    // 1600000
    const int ep = e + n;
    const int* ei0 = ei;
    const int* ei1 = ei + e;
    const int nbuck = (n + 255) >> NBUCK_SHIFT;   // 391

    char* w = (char*)d_ws;
    size_t off = 0;
    auto alloc = [&](size_t b) { size_t o = off; off = (off + b + 255) & ~(size_t)255; return o; };
    float*        x0      = (float*)(w + alloc((size_t)n * 16 * 4));
    float*        x1      = (float*)(w + alloc((size_t)n * 32 * 4));
    float*        x2      = (float*)(w + alloc((size_t)n * 32 * 4));
    float*        x3      = (float*)(w + alloc((size_t)n * 32 * 4));
    unsigned int* h2      = (unsigned int*)(w + alloc((size_t)n * 16 * 4));
    float*        asrc    = (float*)(w + alloc((size_t)n * 4));
    float*        adst    = (float*)(w + alloc((size_t)n * 4));
    uint2*        st      = (uint2*)(w + alloc((size_t)ep * 8));
    uint2*        rec     = (uint2*)(w + alloc((size_t)ep * 8));
    int*          rp      = (int*)(w + alloc((size_t)(n + 1) * 4));
    int*          bcnt    = (int*)(w + alloc(NBUCK_MAX * 4));
    int*          bbase   = (int*)(w + alloc((NBUCK_MAX + 1) * 4));
    int*          bcur    = (int*)(w + alloc(NBUCK_MAX * 4));
    float2*       partial = (float2*)(w + alloc((size_t)8192 * 8));
    float*        consts  = (float*)(w + alloc(256));
    int*          bounds  = (int*)(w + alloc(129 * 4));

    hipMemsetAsync(bcnt, 0, NBUCK_MAX * 4, stream);

    int e4   = e >> 2;
    int nbNE = (n * 16 + 255) / 256;     // 6250
    int nbCS = (e4 + 255) / 256;         // 1563
    int nbH  = (ep + 4095) / 4096;       // 416
    int nw   = nbCS * 4;

    k_pre<<<nbNE + nbCS + nbH + 1, 256, 0, stream>>>(
        nf, W_ne, b_ne, x0, (const float4*)ea, W_ee, b_ee, partial,
        ei1, bcnt, batch, bounds, n, e, ep, nbNE, nbCS, nbH);
    k_mid<<<2, 512, 0, stream>>>(Wel[0], ael[0], Wel[1], ael[1], Wel[2], ael[2],
                                 partial, nw, 1.0f / (float)e, consts,
                                 bcnt, bbase, bcur, nbuck, ep, rp, n);
    k_binB<<<nbH, 256, 0, stream>>>(ei0, ei1, ea, W_ee, b_ee, consts, bcur, st, e, ep);
    k_binC<<<nbuck, 512, 0, stream>>>(st, bbase, rp, rec, n);

    const float* xin = x0;
    float* xo[3] = {x1, x2, x3};
    for (int l = 0; l < 3; ++l) {
        if (l == 0)
            k_hproj<16><<<(n + 7) / 8, 256, 0, stream>>>(xin, Wl[l], asl[l], adl[l],
                                                         h2, asrc, adst, n);
        else
            k_hproj<32><<<(n + 7) / 8, 256, 0, stream>>>(xin, Wl[l], asl[l], adl[l],
                                                         h2, asrc, adst, n);
        k_agg<<<(n + 7) / 8, 256, 0, stream>>>(rp, rec, asrc, adst, consts,
                                               h2, bbl[l], xo[l], n, l);
        xin = xo[l];
    }
    k_dot3<<<128, 256, 0, stream>>>((const float2*)x1, (const float2*)x2,
                                    (const float2*)x3, bounds, W_l3, b_l3,
                                    (float*)d_out);
}

// Round 13
// 361.952 us; speedup vs baseline: 1.2161x; 1.0562x over previous
//
#include <hip/hip_runtime.h>
#include <hip/hip_fp16.h>

// ---------------------------------------------------------------------------
// 3-layer GAT (heads=1) forward. N=100000, E=1600000, Ep=E+N, G=128,
// ND=16, ED=2, H=32.
// R13: chain fusion, zero atomics in hot paths (R2/R4/R9-R11 rule).
//  - k_agg epilogue computes NEXT layer's h via 32-step shfl GEMV (W_{l+1}
//    in LDS) -> h2'/asrc'/adst' ping-pong; x1/x2/x3 never materialized;
//    all 3 k_hproj launches gone.
//  - per-node readout scalar v_l[node] = res . Wl3_l (plain store);
//    k_dotv reads 1.2MB instead of k_dot3's 37.5MB.
//  - layer-0 projection via fused (Wne@W0) 9x32 weight precomputed in k_pre;
//    k_hproj0 reads nf directly; x0 never materialized.
//  - 9 dispatches + memset (was 11+memset).
// Carried: 32-lane agg groups + fp16 h (R8), NT rec loads (R7), LDS bucket
// sort (R6), k_pre/k_mid consolidation (R9), atomic-free readout (R12).
// ---------------------------------------------------------------------------

#define NBUCK_SHIFT 8
#define NBUCK_MAX 512
#define CAP 6144   // max staged edges per 256-node bucket (mean ~4350, max ~4650)

// ---- fused preprocessing: [colsum | hist | (Wf + bounds)] -----------------
__global__ void k_pre(const float4* __restrict__ ea4, const float* __restrict__ Wee,
                      const float* __restrict__ bee, float2* __restrict__ partial,
                      const int* __restrict__ ei1, int* __restrict__ bucket_cnt,
                      const int* __restrict__ batch, int* __restrict__ bounds,
                      const float* __restrict__ Wne, const float* __restrict__ bne,
                      const float* __restrict__ W0, float* __restrict__ wf,
                      int n, int e, int ep, int nbCS, int nbH) {
    int b = blockIdx.x, t = threadIdx.x;
    if (b < nbCS) {
        // ef column sums (self-loop mean fill), 4 edges/thread, no atomics
        int tid = b * 256 + t;
        int e4 = e >> 2;
        float s0 = 0.f, s1 = 0.f;
        if (tid < e4) {
            float4 q0 = ea4[tid * 3], q1 = ea4[tid * 3 + 1], q2 = ea4[tid * 3 + 2];
            float a = q0.x + q0.w + q1.z + q2.y;
            float b2 = q0.y + q1.x + q1.w + q2.z;
            float c = q0.z + q1.y + q2.x + q2.w;
            s0 = a * Wee[0] + b2 * Wee[2] + c * Wee[4] + 4.f * bee[0];
            s1 = a * Wee[1] + b2 * Wee[3] + c * Wee[5] + 4.f * bee[1];
        }
#pragma unroll
        for (int off = 32; off > 0; off >>= 1) {
            s0 += __shfl_xor(s0, off, 64);
            s1 += __shfl_xor(s1, off, 64);
        }
        if ((t & 63) == 0)
            partial[(b << 2) + (t >> 6)] = make_float2(s0, s1);
        return;
    }
    b -= nbCS;
    if (b < nbH) {
        // bucket histogram (bucket = dst>>8), 4096 edges/block, LDS-staged
        __shared__ int lh[NBUCK_MAX];
        lh[t] = 0; lh[t + 256] = 0;
        __syncthreads();
        int base = b * 4096;
#pragma unroll
        for (int i = 0; i < 16; ++i) {
            int gid = base + i * 256 + t;
            if (gid < ep) {
                int d = (gid < e) ? ei1[gid] : gid - e;
                atomicAdd(&lh[d >> NBUCK_SHIFT], 1);
            }
        }
        __syncthreads();
        if (lh[t]) atomicAdd(&bucket_cnt[t], lh[t]);
        if (lh[t + 256]) atomicAdd(&bucket_cnt[t + 256], lh[t + 256]);
        return;
    }
    // last block: fused layer-0 weights Wf = Wne@W0 (9x32), bf = bne@W0,
    // then graph bounds by binary search.
    for (int i = t; i < 288; i += 256) {
        int m = i >> 5, j = i & 31;
        float a = 0.f;
        for (int k = 0; k < 16; ++k) a += Wne[m * 16 + k] * W0[k * 32 + j];
        wf[i] = a;
    }
    if (t < 32) {
        float a = 0.f;
        for (int k = 0; k < 16; ++k) a += bne[k] * W0[k * 32 + t];
        wf[288 + t] = a;
    }
    for (int g = t; g <= 128; g += 256) {
        if (g == 128) { bounds[128] = n; continue; }
        int lo = 0, hi = n;
        while (lo < hi) {
            int mid = (lo + hi) >> 1;
            if (batch[mid] < g) lo = mid + 1; else hi = mid;
        }
        bounds[g] = lo;
    }
}

// Layer-0 projection straight from raw node features (x0 never exists):
// h0 = nf @ Wf + bf.  h stored packed half2.
__global__ void k_hproj0(const float* __restrict__ nf, const float* __restrict__ wf,
                         const float* __restrict__ as_, const float* __restrict__ ad_,
                         unsigned int* __restrict__ h2, float* __restrict__ asrc,
                         float* __restrict__ adst, int n) {
    int node = blockIdx.x * 8 + (threadIdx.x >> 5);
    int j = threadIdx.x & 31;
    if (node >= n) return;
    const float* xr = nf + node * 9;
    float acc = wf[288 + j];
#pragma unroll
    for (int m = 0; m < 9; ++m) acc += xr[m] * wf[m * 32 + j];
    float accp = __shfl_down(acc, 1, 32);
    if ((j & 1) == 0) {
        __half2 hh = __floats2half2_rn(acc, accp);
        h2[(size_t)node * 16 + (j >> 1)] = *reinterpret_cast<unsigned int*>(&hh);
    }
    float r1 = acc * as_[j], r2 = acc * ad_[j];
#pragma unroll
    for (int off = 16; off > 0; off >>= 1) {
        r1 += __shfl_xor(r1, off, 32);
        r2 += __shfl_xor(r2, off, 32);
    }
    if (j == 0) { asrc[node] = r1; adst[node] = r2; }
}

// ---- fused mid: block 0 = consts reduce, block 1 = bucket-base scan -------
__global__ void __launch_bounds__(512)
k_mid(const float* __restrict__ We0, const float* __restrict__ ae0,
      const float* __restrict__ We1, const float* __restrict__ ae1,
      const float* __restrict__ We2, const float* __restrict__ ae2,
      const float2* __restrict__ partial, int nw, float einv,
      float* __restrict__ consts,
      const int* __restrict__ bucket_cnt, int* __restrict__ bucket_base,
      int* __restrict__ bcursor, int nbuck, int ep, int* __restrict__ rp, int n) {
    int t = threadIdx.x;
    if (blockIdx.x == 0) {
        __shared__ float r0[512], r1[512];
        float m0 = 0.f, m1 = 0.f;
        for (int i = t; i < nw; i += 512) {
            float2 v = partial[i];
            m0 += v.x; m1 += v.y;
        }
        r0[t] = m0; r1[t] = m1;
        __syncthreads();
        for (int o = 256; o > 0; o >>= 1) {
            if (t < o) { r0[t] += r0[t + o]; r1[t] += r1[t + o]; }
            __syncthreads();
        }
        if (t == 0) {
            consts[12] = r0[0] * einv;
            consts[13] = r1[0] * einv;
            const float* We[3] = {We0, We1, We2};
            const float* ae[3] = {ae0, ae1, ae2};
            for (int l = 0; l < 3; ++l) {
                float c0 = 0.f, c1 = 0.f;
                for (int j = 0; j < 32; ++j) {
                    c0 += We[l][j] * ae[l][j];
                    c1 += We[l][32 + j] * ae[l][j];
                }
                consts[l * 2 + 0] = c0;
                consts[l * 2 + 1] = c1;
            }
        }
    } else {
        __shared__ int s[512];
        int v = (t < nbuck) ? bucket_cnt[t] : 0;
        s[t] = v;
        __syncthreads();
        for (int o = 1; o < 512; o <<= 1) {
            int x = (t >= o) ? s[t - o] : 0;
            __syncthreads();
            s[t] += x;
            __syncthreads();
        }
        int ex = s[t] - v;
        if (t < nbuck) { bucket_base[t] = ex; bcursor[t] = ex; }
        if (t == 0) { bucket_base[nbuck] = ep; rp[n] = ep; }
    }
}

// Phase B: stage edges grouped by bucket; one 8B uint2 {src<<8|dloc, half2}
// per edge; per-(block,bucket) run reservation keeps stores line-local.
__global__ void k_binB(const int* __restrict__ ei0, const int* __restrict__ ei1,
                       const float* __restrict__ ea, const float* __restrict__ We,
                       const float* __restrict__ be, const float* __restrict__ consts,
                       int* __restrict__ bcursor, uint2* __restrict__ st, int e, int ep) {
    __shared__ int lh[NBUCK_MAX], lcur[NBUCK_MAX];
    int t = threadIdx.x;
    lh[t] = 0; lh[t + 256] = 0;
    __syncthreads();
    int base = blockIdx.x * 4096;
    unsigned int sd[16], fh[16];
    int bk[16];
    float w00 = We[0], w10 = We[2], w20 = We[4];
    float w01 = We[1], w11 = We[3], w21 = We[5];
    float b0 = be[0], b1 = be[1];
#pragma unroll
    for (int i = 0; i < 16; ++i) {
        int gid = base + i * 256 + t;
        bk[i] = -1;
        if (gid < ep) {
            int s, d; float f0, f1;
            if (gid < e) {
                s = ei0[gid]; d = ei1[gid];
                const float* r = ea + (size_t)gid * 3;
                float a0 = r[0], a1 = r[1], a2 = r[2];
                f0 = a0 * w00 + a1 * w10 + a2 * w20 + b0;
                f1 = a0 * w01 + a1 * w11 + a2 * w21 + b1;
            } else {
                s = d = gid - e;
                f0 = consts[12]; f1 = consts[13];
            }
            bk[i] = d >> NBUCK_SHIFT;
            sd[i] = ((unsigned int)s << NBUCK_SHIFT) | (unsigned int)(d & 255);
            __half2 hh = __floats2half2_rn(f0, f1);
            fh[i] = *reinterpret_cast<unsigned int*>(&hh);
            atomicAdd(&lh[bk[i]], 1);
        }
    }
    __syncthreads();
    if (lh[t] > 0) lcur[t] = atomicAdd(&bcursor[t], lh[t]);
    if (lh[t + 256] > 0) lcur[t + 256] = atomicAdd(&bcursor[t + 256], lh[t + 256]);
    __syncthreads();
#pragma unroll
    for (int i = 0; i < 16; ++i) {
        if (bk[i] >= 0) {
            int pos = atomicAdd(&lcur[bk[i]], 1);
            st[pos] = make_uint2(sd[i], fh[i]);
        }
    }
}

// Phase C: one 512-thread block per bucket. LDS node-hist + scan -> rp
// coalesced; scatter into LDS-sorted buffer; stream out coalesced.
__global__ void __launch_bounds__(512)
k_binC(const uint2* __restrict__ st, const int* __restrict__ bucket_base,
       int* __restrict__ rp, uint2* __restrict__ rec, int n) {
    __shared__ int nh[256], ns[256];
    __shared__ uint2 rs[CAP];
    int k = blockIdx.x, t = threadIdx.x;
    int s0 = bucket_base[k], s1 = bucket_base[k + 1];
    int cnt = s1 - s0;
    if (t < 256) nh[t] = 0;
    __syncthreads();
    for (int i = s0 + t; i < s1; i += 512)
        atomicAdd(&nh[st[i].x & 255], 1);
    __syncthreads();
    if (t < 256) ns[t] = nh[t];
    __syncthreads();
    for (int o = 1; o < 256; o <<= 1) {
        int add = 0;
        if (t < 256 && t >= o) add = ns[t - o];
        __syncthreads();
        if (t < 256) ns[t] += add;
        __syncthreads();
    }
    int node0 = k << NBUCK_SHIFT;
    if (t < 256) {
        int startl = ns[t] - nh[t];      // exclusive, bucket-local
        if (node0 + t < n) rp[node0 + t] = s0 + startl;
        nh[t] = startl;                  // becomes local cursor
    }
    __syncthreads();
    for (int i = s0 + t; i < s1; i += 512) {
        uint2 v = st[i];
        int pos = atomicAdd(&nh[v.x & 255], 1);
        uint2 r = make_uint2(v.x >> NBUCK_SHIFT, v.y);
        if (pos < CAP) rs[pos] = r;
        else rec[s0 + pos] = r;          // overflow fallback (never in practice)
    }
    __syncthreads();
    int m = cnt < CAP ? cnt : CAP;
    for (int i = t; i < m; i += 512)
        rec[s0 + i] = rs[i];
}

__device__ __forceinline__ float h2_get(const unsigned int* __restrict__ h2,
                                        int s, int word, bool hi) {
    unsigned int hw = h2[(size_t)s * 16 + word];
    __half2 hh = *reinterpret_cast<__half2*>(&hw);
    return hi ? __high2float(hh) : __low2float(hh);
}

// Fused edge-softmax + aggregation, 32-lane group per dst node (R8 body).
// Epilogue (no atomics): v[node] = res . wl3 slice (plain store);
// HAS_NEXT: next layer's h via 32-step shfl GEMV against sW (LDS) ->
// h2out (fp16 packed) + asrcOut/adstOut. x_l never hits memory.
template <bool HAS_NEXT>
__global__ void k_agg(const int* __restrict__ rp, const uint2* __restrict__ rec,
                      const float* __restrict__ asrcIn, const float* __restrict__ adstIn,
                      const float* __restrict__ consts, const unsigned int* __restrict__ h2in,
                      const float* __restrict__ bb, const float* __restrict__ Wn,
                      const float* __restrict__ asn, const float* __restrict__ adn_,
                      unsigned int* __restrict__ h2out, float* __restrict__ asrcOut,
                      float* __restrict__ adstOut, const float* __restrict__ wl3,
                      float* __restrict__ vout, int n, int layer) {
    __shared__ float sW[1024];
    if (HAS_NEXT) {
        for (int i = threadIdx.x; i < 1024; i += 256) sW[i] = Wn[i];
        __syncthreads();
    }
    int node = blockIdx.x * 8 + (threadIdx.x >> 5);
    int j = threadIdx.x & 31;
    if (node >= n) return;
    float c0 = consts[layer * 2], c1 = consts[layer * 2 + 1];
    int r0 = rp[node], r1 = rp[node + 1];
    float adn = adstIn[node];
    int word = j >> 1;
    bool hi = (j & 1) != 0;
    float acc = 0.f, psum = 0.f;
    for (int c = r0; c < r1; c += 32) {
        int i = c + j;
        float pe = 0.f; int s = 0;
        if (i < r1) {
            unsigned long long rv = __builtin_nontemporal_load(
                reinterpret_cast<const unsigned long long*>(rec + i));
            s = (int)(unsigned int)(rv & 0xffffffffull);
            unsigned int fv = (unsigned int)(rv >> 32);
            __half2 hh = *reinterpret_cast<__half2*>(&fv);
            float lg = asrcIn[s] + adn + __low2float(hh) * c0 + __high2float(hh) * c1;
            lg = lg > 0.f ? lg : 0.2f * lg;
            pe = __expf(lg);
        }
        psum += pe;
        int cnt = min(32, r1 - c);
        int t = 0;
        for (; t + 8 <= cnt; t += 8) {
            int s0 = __shfl(s, t, 32),     s1 = __shfl(s, t + 1, 32);
            int s2 = __shfl(s, t + 2, 32), s3 = __shfl(s, t + 3, 32);
            int s4 = __shfl(s, t + 4, 32), s5 = __shfl(s, t + 5, 32);
            int s6 = __shfl(s, t + 6, 32), s7 = __shfl(s, t + 7, 32);
            float p0 = __shfl(pe, t, 32),     p1 = __shfl(pe, t + 1, 32);
            float p2 = __shfl(pe, t + 2, 32), p3 = __shfl(pe, t + 3, 32);
            float p4 = __shfl(pe, t + 4, 32), p5 = __shfl(pe, t + 5, 32);
            float p6 = __shfl(pe, t + 6, 32), p7 = __shfl(pe, t + 7, 32);
            float h0 = h2_get(h2in, s0, word, hi);
            float h1 = h2_get(h2in, s1, word, hi);
            float h2v = h2_get(h2in, s2, word, hi);
            float h3 = h2_get(h2in, s3, word, hi);
            float h4 = h2_get(h2in, s4, word, hi);
            float h5 = h2_get(h2in, s5, word, hi);
            float h6 = h2_get(h2in, s6, word, hi);
            float h7 = h2_get(h2in, s7, word, hi);
            acc += p0 * h0; acc += p1 * h1; acc += p2 * h2v; acc += p3 * h3;
            acc += p4 * h4; acc += p5 * h5; acc += p6 * h6; acc += p7 * h7;
        }
        for (; t + 4 <= cnt; t += 4) {
            int s0 = __shfl(s, t, 32),     s1 = __shfl(s, t + 1, 32);
            int s2 = __shfl(s, t + 2, 32), s3 = __shfl(s, t + 3, 32);
            float p0 = __shfl(pe, t, 32),     p1 = __shfl(pe, t + 1, 32);
            float p2 = __shfl(pe, t + 2, 32), p3 = __shfl(pe, t + 3, 32);
            float h0 = h2_get(h2in, s0, word, hi);
            float h1 = h2_get(h2in, s1, word, hi);
            float h2v = h2_get(h2in, s2, word, hi);
            float h3 = h2_get(h2in, s3, word, hi);
            acc += p0 * h0; acc += p1 * h1; acc += p2 * h2v; acc += p3 * h3;
        }
        for (; t < cnt; ++t) {
            int st2 = __shfl(s, t, 32);
            float pt = __shfl(pe, t, 32);
            acc += pt * h2_get(h2in, st2, word, hi);
        }
    }
#pragma unroll
    for (int off = 16; off > 0; off >>= 1) psum += __shfl_xor(psum, off, 32);
    float res = acc / (psum + 1e-16f) + bb[j];   // == x_{l+1}[node][j]
    // readout contribution (atomic-free: one plain store per node)
    float v = res * wl3[j];
#pragma unroll
    for (int off = 16; off > 0; off >>= 1) v += __shfl_xor(v, off, 32);
    if (j == 0) vout[node] = v;
    if (HAS_NEXT) {
        // next-layer projection: hn_j = sum_k res_k * W[k][j]
        float hn = 0.f;
#pragma unroll
        for (int k = 0; k < 32; ++k)
            hn += __shfl(res, k, 32) * sW[k * 32 + j];
        float hnp = __shfl_down(hn, 1, 32);
        if ((j & 1) == 0) {
            __half2 hh = __floats2half2_rn(hn, hnp);
            h2out[(size_t)node * 16 + (j >> 1)] = *reinterpret_cast<unsigned int*>(&hh);
        }
        float r1n = hn * asn[j], r2n = hn * adn_[j];
#pragma unroll
        for (int off = 16; off > 0; off >>= 1) {
            r1n += __shfl_xor(r1n, off, 32);
            r2n += __shfl_xor(r2n, off, 32);
        }
        if (j == 0) { asrcOut[node] = r1n; adstOut[node] = r2n; }
    }
}

// Readout: one block per graph, sums the three per-node scalars. 1.2MB total.
__global__ void k_dotv(const float* __restrict__ v0, const float* __restrict__ v1,
                       const float* __restrict__ v2, const int* __restrict__ bounds,
                       const float* __restrict__ bl3, float* __restrict__ out) {
    __shared__ float red[256];
    int g = blockIdx.x, t = threadIdx.x;
    int s0 = bounds[g], s1 = bounds[g + 1];
    float acc = 0.f;
    for (int i = s0 + t; i < s1; i += 256) acc += v0[i] + v1[i] + v2[i];
    red[t] = acc;
    __syncthreads();
    for (int o = 128; o > 0; o >>= 1) {
        if (t < o) red[t] += red[t + o];
        __syncthreads();
    }
    if (t == 0) {
        float c = (float)(s1 - s0);
        if (c < 1.f) c = 1.f;
        out[g] = red[0] / c + bl3[0];
    }
}

extern "C" void kernel_launch(void* const* d_in, const int* in_sizes, int n_in,
                              void* d_out, int out_size, void* d_ws, size_t ws_size,
                              hipStream_t stream) {
    (void)n_in; (void)out_size; (void)ws_size;
    const float* nf    = (const float*)d_in[0];
    const int*   ei    = (const int*)d_in[1];
    const float* ea    = (const float*)d_in[2];
    const int*   batch = (const int*)d_in[3];
    const float* W_ne  = (const float*)d_in[4];
    const float* b_ne  = (const float*)d_in[5];
    const float* W_ee  = (const float*)d_in[6];
    const float* b_ee  = (const float*)d_in[7];
    const float* W_l3  = (const float*)d_in[8];
    const float* b_l3  = (const float*)d_in[9];
    const float *Wl[3], *asl[3], *adl[3], *Wel[3], *ael[3], *bbl[3];
    for (int l = 0; l < 3; ++l) {
        Wl[l]  = (const float*)d_in[10 + 6 * l];
        asl[l] = (const float*)d_in[11 + 6 * l];
        adl[l] = (const float*)d_in[12 + 6 * l];
        Wel[l] = (const float*)d_in[13 + 6 * l];
        ael[l] = (const float*)d_in[14 + 6 * l];
        bbl[l] = (const float*)d_in[15 + 6 * l];
    }

    const int n  = in_sizes[3];        // 100000
    const int e  = in_sizes[2] / 3;    // 1600000
    const int ep = e + n;
    const int* ei0 = ei;
    const int* ei1 = ei + e;
    const int nbuck = (n + 255) >> NBUCK_SHIFT;   // 391

    char* w = (char*)d_ws;
    size_t off = 0;
    auto alloc = [&](size_t b) { size_t o = off; off = (off + b + 255) & ~(size_t)255; return o; };
    unsigned int* h2a     = (unsigned int*)(w + alloc((size_t)n * 16 * 4));
    unsigned int* h2b     = (unsigned int*)(w + alloc((size_t)n * 16 * 4));
    float*        asrcA   = (float*)(w + alloc((size_t)n * 4));
    float*        adstA   = (float*)(w + alloc((size_t)n * 4));
    float*        asrcB   = (float*)(w + alloc((size_t)n * 4));
    float*        adstB   = (float*)(w + alloc((size_t)n * 4));
    float*        v0      = (float*)(w + alloc((size_t)n * 4));
    float*        v1      = (float*)(w + alloc((size_t)n * 4));
    float*        v2      = (float*)(w + alloc((size_t)n * 4));
    uint2*        st      = (uint2*)(w + alloc((size_t)ep * 8));
    uint2*        rec     = (uint2*)(w + alloc((size_t)ep * 8));
    int*          rp      = (int*)(w + alloc((size_t)(n + 1) * 4));
    int*          bcnt    = (int*)(w + alloc(NBUCK_MAX * 4));
    int*          bbase   = (int*)(w + alloc((NBUCK_MAX + 1) * 4));
    int*          bcur    = (int*)(w + alloc(NBUCK_MAX * 4));
    float2*       partial = (float2*)(w + alloc((size_t)8192 * 8));
    float*        consts  = (float*)(w + alloc(256));
    int*          bounds  = (int*)(w + alloc(129 * 4));
    float*        wfbuf   = (float*)(w + alloc(320 * 4));

    hipMemsetAsync(bcnt, 0, NBUCK_MAX * 4, stream);

    int e4   = e >> 2;
    int nbCS = (e4 + 255) / 256;         // 1563
    int nbH  = (ep + 4095) / 4096;       // 416
    int nw   = nbCS * 4;
    int nbN  = (n + 7) / 8;              // 12500

    k_pre<<<nbCS + nbH + 1, 256, 0, stream>>>(
        (const float4*)ea, W_ee, b_ee, partial, ei1, bcnt, batch, bounds,
        W_ne, b_ne, Wl[0], wfbuf, n, e, ep, nbCS, nbH);
    k_hproj0<<<nbN, 256, 0, stream>>>(nf, wfbuf, asl[0], adl[0],
                                      h2a, asrcA, adstA, n);
    k_mid<<<2, 512, 0, stream>>>(Wel[0], ael[0], Wel[1], ael[1], Wel[2], ael[2],
                                 partial, nw, 1.0f / (float)e, consts,
                                 bcnt, bbase, bcur, nbuck, ep, rp, n);
    k_binB<<<nbH, 256, 0, stream>>>(ei0, ei1, ea, W_ee, b_ee, consts, bcur, st, e, ep);
    k_binC<<<nbuck, 512, 0, stream>>>(st, bbase, rp, rec, n);

    // layer 0: reads h2a/A, writes h2b/B (+v0)
    k_agg<true><<<nbN, 256, 0, stream>>>(rp, rec, asrcA, adstA, consts, h2a,
                                         bbl[0], Wl[1], asl[1], adl[1],
                                         h2b, asrcB, adstB, W_l3 + 0, v0, n, 0);
    // layer 1: reads h2b/B, writes h2a/A (+v1)
    k_agg<true><<<nbN, 256, 0, stream>>>(rp, rec, asrcB, adstB, consts, h2b,
                                         bbl[1], Wl[2], asl[2], adl[2],
                                         h2a, asrcA, adstA, W_l3 + 32, v1, n, 1);
    // layer 2: reads h2a/A, writes only v2
    k_agg<false><<<nbN, 256, 0, stream>>>(rp, rec, asrcA, adstA, consts, h2a,
                                          bbl[2], nullptr, nullptr, nullptr,
                                          nullptr, nullptr, nullptr,
                                          W_l3 + 64, v2, n, 2);
    k_dotv<<<128, 256, 0, stream>>>(v0, v1, v2, bounds, b_l3, (float*)d_out);
}

// Round 14
// 348.301 us; speedup vs baseline: 1.2638x; 1.0392x over previous
//
#include <hip/hip_runtime.h>
#include <hip/hip_fp16.h>

// ---------------------------------------------------------------------------
// 3-layer GAT (heads=1) forward. N=100000, E=1600000, Ep=E+N, G=128,
// ND=16, ED=2, H=32.
// R14: recombination. R13 lesson: in-agg shfl-GEMV epilogue = +29us/layer of
// non-overlappable DS-pipe tail (vs 8us standalone hproj). k_agg back to the
// proven R12 body + cheap epilogue (fp32 x store + per-node v scalar);
// separate k_hproj for layers 1/2. Kept from R13: hproj0 (Wne@W0 fused, x0
// never exists), v-scalar readout (k_dotv, 1.2MB), no x3 materialization.
// New: k_binC single-pass (staged recs held in registers; st read once).
// Carried: 32-lane agg groups + fp16 h (R8), NT rec loads (R7), LDS bucket
// sort (R6), k_pre/k_mid consolidation (R9), no-atomics rule (R2/R4/R9-R11).
// ---------------------------------------------------------------------------

#define NBUCK_SHIFT 8
#define NBUCK_MAX 512
#define CAP 6144   // max staged edges per 256-node bucket (mean ~4350, max ~4650)

// ---- fused preprocessing: [colsum | hist | (Wf + bounds)] -----------------
__global__ void k_pre(const float4* __restrict__ ea4, const float* __restrict__ Wee,
                      const float* __restrict__ bee, float2* __restrict__ partial,
                      const int* __restrict__ ei1, int* __restrict__ bucket_cnt,
                      const int* __restrict__ batch, int* __restrict__ bounds,
                      const float* __restrict__ Wne, const float* __restrict__ bne,
                      const float* __restrict__ W0, float* __restrict__ wf,
                      int n, int e, int ep, int nbCS, int nbH) {
    int b = blockIdx.x, t = threadIdx.x;
    if (b < nbCS) {
        int tid = b * 256 + t;
        int e4 = e >> 2;
        float s0 = 0.f, s1 = 0.f;
        if (tid < e4) {
            float4 q0 = ea4[tid * 3], q1 = ea4[tid * 3 + 1], q2 = ea4[tid * 3 + 2];
            float a = q0.x + q0.w + q1.z + q2.y;
            float b2 = q0.y + q1.x + q1.w + q2.z;
            float c = q0.z + q1.y + q2.x + q2.w;
            s0 = a * Wee[0] + b2 * Wee[2] + c * Wee[4] + 4.f * bee[0];
            s1 = a * Wee[1] + b2 * Wee[3] + c * Wee[5] + 4.f * bee[1];
        }
#pragma unroll
        for (int off = 32; off > 0; off >>= 1) {
            s0 += __shfl_xor(s0, off, 64);
            s1 += __shfl_xor(s1, off, 64);
        }
        if ((t & 63) == 0)
            partial[(b << 2) + (t >> 6)] = make_float2(s0, s1);
        return;
    }
    b -= nbCS;
    if (b < nbH) {
        __shared__ int lh[NBUCK_MAX];
        lh[t] = 0; lh[t + 256] = 0;
        __syncthreads();
        int base = b * 4096;
#pragma unroll
        for (int i = 0; i < 16; ++i) {
            int gid = base + i * 256 + t;
            if (gid < ep) {
                int d = (gid < e) ? ei1[gid] : gid - e;
                atomicAdd(&lh[d >> NBUCK_SHIFT], 1);
            }
        }
        __syncthreads();
        if (lh[t]) atomicAdd(&bucket_cnt[t], lh[t]);
        if (lh[t + 256]) atomicAdd(&bucket_cnt[t + 256], lh[t + 256]);
        return;
    }
    // last block: fused layer-0 weights Wf = Wne@W0 (9x32), bf = bne@W0,
    // then graph bounds by binary search.
    for (int i = t; i < 288; i += 256) {
        int m = i >> 5, j = i & 31;
        float a = 0.f;
        for (int k = 0; k < 16; ++k) a += Wne[m * 16 + k] * W0[k * 32 + j];
        wf[i] = a;
    }
    if (t < 32) {
        float a = 0.f;
        for (int k = 0; k < 16; ++k) a += bne[k] * W0[k * 32 + t];
        wf[288 + t] = a;
    }
    for (int g = t; g <= 128; g += 256) {
        if (g == 128) { bounds[128] = n; continue; }
        int lo = 0, hi = n;
        while (lo < hi) {
            int mid = (lo + hi) >> 1;
            if (batch[mid] < g) lo = mid + 1; else hi = mid;
        }
        bounds[g] = lo;
    }
}

// Layer-0 projection straight from raw node features (x0 never exists):
// h0 = nf @ Wf + bf.  h stored packed half2.
__global__ void k_hproj0(const float* __restrict__ nf, const float* __restrict__ wf,
                         const float* __restrict__ as_, const float* __restrict__ ad_,
                         unsigned int* __restrict__ h2, float* __restrict__ asrc,
                         float* __restrict__ adst, int n) {
    int node = blockIdx.x * 8 + (threadIdx.x >> 5);
    int j = threadIdx.x & 31;
    if (node >= n) return;
    const float* xr = nf + node * 9;
    float acc = wf[288 + j];
#pragma unroll
    for (int m = 0; m < 9; ++m) acc += xr[m] * wf[m * 32 + j];
    float accp = __shfl_down(acc, 1, 32);
    if ((j & 1) == 0) {
        __half2 hh = __floats2half2_rn(acc, accp);
        h2[(size_t)node * 16 + (j >> 1)] = *reinterpret_cast<unsigned int*>(&hh);
    }
    float r1 = acc * as_[j], r2 = acc * ad_[j];
#pragma unroll
    for (int off = 16; off > 0; off >>= 1) {
        r1 += __shfl_xor(r1, off, 32);
        r2 += __shfl_xor(r2, off, 32);
    }
    if (j == 0) { asrc[node] = r1; adst[node] = r2; }
}

// Mid-layer projection: h = x @ W (x fp32, W in LDS), h stored packed half2.
__global__ void k_hproj(const float* __restrict__ x, const float* __restrict__ W,
                        const float* __restrict__ as_, const float* __restrict__ ad_,
                        unsigned int* __restrict__ h2, float* __restrict__ asrc,
                        float* __restrict__ adst, int n) {
    __shared__ float sW[1024];
    for (int i = threadIdx.x; i < 1024; i += 256) sW[i] = W[i];
    __syncthreads();
    int node = blockIdx.x * 8 + (threadIdx.x >> 5);
    int j = threadIdx.x & 31;
    if (node >= n) return;
    const float* xr = x + (size_t)node * 32;
    float acc = 0.f;
#pragma unroll
    for (int k = 0; k < 32; ++k) acc += xr[k] * sW[k * 32 + j];
    float accp = __shfl_down(acc, 1, 32);
    if ((j & 1) == 0) {
        __half2 hh = __floats2half2_rn(acc, accp);
        h2[(size_t)node * 16 + (j >> 1)] = *reinterpret_cast<unsigned int*>(&hh);
    }
    float r1 = acc * as_[j], r2 = acc * ad_[j];
#pragma unroll
    for (int off = 16; off > 0; off >>= 1) {
        r1 += __shfl_xor(r1, off, 32);
        r2 += __shfl_xor(r2, off, 32);
    }
    if (j == 0) { asrc[node] = r1; adst[node] = r2; }
}

// ---- fused mid: block 0 = consts reduce, block 1 = bucket-base scan -------
__global__ void __launch_bounds__(512)
k_mid(const float* __restrict__ We0, const float* __restrict__ ae0,
      const float* __restrict__ We1, const float* __restrict__ ae1,
      const float* __restrict__ We2, const float* __restrict__ ae2,
      const float2* __restrict__ partial, int nw, float einv,
      float* __restrict__ consts,
      const int* __restrict__ bucket_cnt, int* __restrict__ bucket_base,
      int* __restrict__ bcursor, int nbuck, int ep, int* __restrict__ rp, int n) {
    int t = threadIdx.x;
    if (blockIdx.x == 0) {
        __shared__ float r0[512], r1[512];
        float m0 = 0.f, m1 = 0.f;
        for (int i = t; i < nw; i += 512) {
            float2 v = partial[i];
            m0 += v.x; m1 += v.y;
        }
        r0[t] = m0; r1[t] = m1;
        __syncthreads();
        for (int o = 256; o > 0; o >>= 1) {
            if (t < o) { r0[t] += r0[t + o]; r1[t] += r1[t + o]; }
            __syncthreads();
        }
        if (t == 0) {
            consts[12] = r0[0] * einv;
            consts[13] = r1[0] * einv;
            const float* We[3] = {We0, We1, We2};
            const float* ae[3] = {ae0, ae1, ae2};
            for (int l = 0; l < 3; ++l) {
                float c0 = 0.f, c1 = 0.f;
                for (int j = 0; j < 32; ++j) {
                    c0 += We[l][j] * ae[l][j];
                    c1 += We[l][32 + j] * ae[l][j];
                }
                consts[l * 2 + 0] = c0;
                consts[l * 2 + 1] = c1;
            }
        }
    } else {
        __shared__ int s[512];
        int v = (t < nbuck) ? bucket_cnt[t] : 0;
        s[t] = v;
        __syncthreads();
        for (int o = 1; o < 512; o <<= 1) {
            int x = (t >= o) ? s[t - o] : 0;
            __syncthreads();
            s[t] += x;
            __syncthreads();
        }
        int ex = s[t] - v;
        if (t < nbuck) { bucket_base[t] = ex; bcursor[t] = ex; }
        if (t == 0) { bucket_base[nbuck] = ep; rp[n] = ep; }
    }
}

// Phase B: stage edges grouped by bucket; one 8B uint2 {src<<8|dloc, half2}
// per edge; per-(block,bucket) run reservation keeps stores line-local.
__global__ void k_binB(const int* __restrict__ ei0, const int* __restrict__ ei1,
                       const float* __restrict__ ea, const float* __restrict__ We,
                       const float* __restrict__ be, const float* __restrict__ consts,
                       int* __restrict__ bcursor, uint2* __restrict__ st, int e, int ep) {
    __shared__ int lh[NBUCK_MAX], lcur[NBUCK_MAX];
    int t = threadIdx.x;
    lh[t] = 0; lh[t + 256] = 0;
    __syncthreads();
    int base = blockIdx.x * 4096;
    unsigned int sd[16], fh[16];
    int bk[16];
    float w00 = We[0], w10 = We[2], w20 = We[4];
    float w01 = We[1], w11 = We[3], w21 = We[5];
    float b0 = be[0], b1 = be[1];
#pragma unroll
    for (int i = 0; i < 16; ++i) {
        int gid = base + i * 256 + t;
        bk[i] = -1;
        if (gid < ep) {
            int s, d; float f0, f1;
            if (gid < e) {
                s = ei0[gid]; d = ei1[gid];
                const float* r = ea + (size_t)gid * 3;
                float a0 = r[0], a1 = r[1], a2 = r[2];
                f0 = a0 * w00 + a1 * w10 + a2 * w20 + b0;
                f1 = a0 * w01 + a1 * w11 + a2 * w21 + b1;
            } else {
                s = d = gid - e;
                f0 = consts[12]; f1 = consts[13];
            }
            bk[i] = d >> NBUCK_SHIFT;
            sd[i] = ((unsigned int)s << NBUCK_SHIFT) | (unsigned int)(d & 255);
            __half2 hh = __floats2half2_rn(f0, f1);
            fh[i] = *reinterpret_cast<unsigned int*>(&hh);
            atomicAdd(&lh[bk[i]], 1);
        }
    }
    __syncthreads();
    if (lh[t] > 0) lcur[t] = atomicAdd(&bcursor[t], lh[t]);
    if (lh[t + 256] > 0) lcur[t + 256] = atomicAdd(&bcursor[t + 256], lh[t + 256]);
    __syncthreads();
#pragma unroll
    for (int i = 0; i < 16; ++i) {
        if (bk[i] >= 0) {
            int pos = atomicAdd(&lcur[bk[i]], 1);
            st[pos] = make_uint2(sd[i], fh[i]);
        }
    }
}

// Phase C, single-pass: staged recs held in registers (<=12/thread) during
// the hist pass; st read ONCE (was twice). LDS scatter -> coalesced out.
__global__ void __launch_bounds__(512)
k_binC(const uint2* __restrict__ st, const int* __restrict__ bucket_base,
       int* __restrict__ rp, uint2* __restrict__ rec, int n) {
    __shared__ int nh[256], ns[256];
    __shared__ uint2 rs[CAP];
    int k = blockIdx.x, t = threadIdx.x;
    int s0 = bucket_base[k], s1 = bucket_base[k + 1];
    int cnt = s1 - s0;
    uint2 lv[12];
    if (t < 256) nh[t] = 0;
    __syncthreads();
#pragma unroll
    for (int u = 0; u < 12; ++u) {
        int i = s0 + u * 512 + t;
        if (i < s1) {
            uint2 v = st[i];
            lv[u] = v;
            atomicAdd(&nh[v.x & 255], 1);
        }
    }
    __syncthreads();
    if (t < 256) ns[t] = nh[t];
    __syncthreads();
    for (int o = 1; o < 256; o <<= 1) {
        int add = 0;
        if (t < 256 && t >= o) add = ns[t - o];
        __syncthreads();
        if (t < 256) ns[t] += add;
        __syncthreads();
    }
    int node0 = k << NBUCK_SHIFT;
    if (t < 256) {
        int startl = ns[t] - nh[t];      // exclusive, bucket-local
        if (node0 + t < n) rp[node0 + t] = s0 + startl;
        nh[t] = startl;                  // becomes local cursor
    }
    __syncthreads();
#pragma unroll
    for (int u = 0; u < 12; ++u) {
        int i = s0 + u * 512 + t;
        if (i < s1) {
            uint2 v = lv[u];
            int pos = atomicAdd(&nh[v.x & 255], 1);
            uint2 r = make_uint2(v.x >> NBUCK_SHIFT, v.y);
            if (pos < CAP) rs[pos] = r;
            else rec[s0 + pos] = r;      // overflow fallback (never in practice)
        }
    }
    __syncthreads();
    int m = cnt < CAP ? cnt : CAP;
    for (int i = t; i < m; i += 512)
        rec[s0 + i] = rs[i];
}

__device__ __forceinline__ float h2_get(const unsigned int* __restrict__ h2,
                                        int s, int word, bool hi) {
    unsigned int hw = h2[(size_t)s * 16 + word];
    __half2 hh = *reinterpret_cast<__half2*>(&hw);
    return hi ? __high2float(hh) : __low2float(hh);
}

// Fused edge-softmax + aggregation, 32-lane group per dst node (R8 body).
// Epilogue (cheap, no atomics, no GEMV -- R13 lesson): optional fp32 x store
// + per-node readout scalar v[node] = res . wl3 (plain store).
template <bool STORE_X>
__global__ void k_agg(const int* __restrict__ rp, const uint2* __restrict__ rec,
                      const float* __restrict__ asrc, const float* __restrict__ adst,
                      const float* __restrict__ consts, const unsigned int* __restrict__ h2,
                      const float* __restrict__ bb, float* __restrict__ xout,
                      const float* __restrict__ wl3, float* __restrict__ vout,
                      int n, int layer) {
    int node = blockIdx.x * 8 + (threadIdx.x >> 5);
    int j = threadIdx.x & 31;
    if (node >= n) return;
    float c0 = consts[layer * 2], c1 = consts[layer * 2 + 1];
    int r0 = rp[node], r1 = rp[node + 1];
    float adn = adst[node];
    int word = j >> 1;
    bool hi = (j & 1) != 0;
    float acc = 0.f, psum = 0.f;
    for (int c = r0; c < r1; c += 32) {
        int i = c + j;
        float pe = 0.f; int s = 0;
        if (i < r1) {
            unsigned long long rv = __builtin_nontemporal_load(
                reinterpret_cast<const unsigned long long*>(rec + i));
            s = (int)(unsigned int)(rv & 0xffffffffull);
            unsigned int fv = (unsigned int)(rv >> 32);
            __half2 hh = *reinterpret_cast<__half2*>(&fv);
            float lg = asrc[s] + adn + __low2float(hh) * c0 + __high2float(hh) * c1;
            lg = lg > 0.f ? lg : 0.2f * lg;
            pe = __expf(lg);
        }
        psum += pe;
        int cnt = min(32, r1 - c);
        int t = 0;
        for (; t + 8 <= cnt; t += 8) {
            int s0 = __shfl(s, t, 32),     s1 = __shfl(s, t + 1, 32);
            int s2 = __shfl(s, t + 2, 32), s3 = __shfl(s, t + 3, 32);
            int s4 = __shfl(s, t + 4, 32), s5 = __shfl(s, t + 5, 32);
            int s6 = __shfl(s, t + 6, 32), s7 = __shfl(s, t + 7, 32);
            float p0 = __shfl(pe, t, 32),     p1 = __shfl(pe, t + 1, 32);
            float p2 = __shfl(pe, t + 2, 32), p3 = __shfl(pe, t + 3, 32);
            float p4 = __shfl(pe, t + 4, 32), p5 = __shfl(pe, t + 5, 32);
            float p6 = __shfl(pe, t + 6, 32), p7 = __shfl(pe, t + 7, 32);
            float h0 = h2_get(h2, s0, word, hi);
            float h1 = h2_get(h2, s1, word, hi);
            float h2v = h2_get(h2, s2, word, hi);
            float h3 = h2_get(h2, s3, word, hi);
            float h4 = h2_get(h2, s4, word, hi);
            float h5 = h2_get(h2, s5, word, hi);
            float h6 = h2_get(h2, s6, word, hi);
            float h7 = h2_get(h2, s7, word, hi);
            acc += p0 * h0; acc += p1 * h1; acc += p2 * h2v; acc += p3 * h3;
            acc += p4 * h4; acc += p5 * h5; acc += p6 * h6; acc += p7 * h7;
        }
        for (; t + 4 <= cnt; t += 4) {
            int s0 = __shfl(s, t, 32),     s1 = __shfl(s, t + 1, 32);
            int s2 = __shfl(s, t + 2, 32), s3 = __shfl(s, t + 3, 32);
            float p0 = __shfl(pe, t, 32),     p1 = __shfl(pe, t + 1, 32);
            float p2 = __shfl(pe, t + 2, 32), p3 = __shfl(pe, t + 3, 32);
            float h0 = h2_get(h2, s0, word, hi);
            float h1 = h2_get(h2, s1, word, hi);
            float h2v = h2_get(h2, s2, word, hi);
            float h3 = h2_get(h2, s3, word, hi);
            acc += p0 * h0; acc += p1 * h1; acc += p2 * h2v; acc += p3 * h3;
        }
        for (; t < cnt; ++t) {
            int st2 = __shfl(s, t, 32);
            float pt = __shfl(pe, t, 32);
            acc += pt * h2_get(h2, st2, word, hi);
        }
    }
#pragma unroll
    for (int off = 16; off > 0; off >>= 1) psum += __shfl_xor(psum, off, 32);
    float res = acc / (psum + 1e-16f) + bb[j];
    if (STORE_X) xout[(size_t)node * 32 + j] = res;
    float v = res * wl3[j];
#pragma unroll
    for (int off = 16; off > 0; off >>= 1) v += __shfl_xor(v, off, 32);
    if (j == 0) vout[node] = v;
}

// Readout: one block per graph, sums the three per-node scalars. 1.2MB total.
__global__ void k_dotv(const float* __restrict__ v0, const float* __restrict__ v1,
                       const float* __restrict__ v2, const int* __restrict__ bounds,
                       const float* __restrict__ bl3, float* __restrict__ out) {
    __shared__ float red[256];
    int g = blockIdx.x, t = threadIdx.x;
    int s0 = bounds[g], s1 = bounds[g + 1];
    float acc = 0.f;
    for (int i = s0 + t; i < s1; i += 256) acc += v0[i] + v1[i] + v2[i];
    red[t] = acc;
    __syncthreads();
    for (int o = 128; o > 0; o >>= 1) {
        if (t < o) red[t] += red[t + o];
        __syncthreads();
    }
    if (t == 0) {
        float c = (float)(s1 - s0);
        if (c < 1.f) c = 1.f;
        out[g] = red[0] / c + bl3[0];
    }
}

extern "C" void kernel_launch(void* const* d_in, const int* in_sizes, int n_in,
                              void* d_out, int out_size, void* d_ws, size_t ws_size,
                              hipStream_t stream) {
    (void)n_in; (void)out_size; (void)ws_size;
    const float* nf    = (const float*)d_in[0];
    const int*   ei    = (const int*)d_in[1];
    const float* ea    = (const float*)d_in[2];
    const int*   batch = (const int*)d_in[3];
    const float* W_ne  = (const float*)d_in[4];
    const float* b_ne  = (const float*)d_in[5];
    const float* W_ee  = (const float*)d_in[6];
    const float* b_ee  = (const float*)d_in[7];
    const float* W_l3  = (const float*)d_in[8];
    const float* b_l3  = (const float*)d_in[9];
    const float *Wl[3], *asl[3], *adl[3], *Wel[3], *ael[3], *bbl[3];
    for (int l = 0; l < 3; ++l) {
        Wl[l]  = (const float*)d_in[10 + 6 * l];
        asl[l] = (const float*)d_in[11 + 6 * l];
        adl[l] = (const float*)d_in[12 + 6 * l];
        Wel[l] = (const float*)d_in[13 + 6 * l];
        ael[l] = (const float*)d_in[14 + 6 * l];
        bbl[l] = (const float*)d_in[15 + 6 * l];
    }

    const int n  = in_sizes[3];        // 100000
    const int e  = in_sizes[2] / 3;    // 1600000
    const int ep = e + n;
    const int* ei0 = ei;
    const int* ei1 = ei + e;
    const int nbuck = (n + 255) >> NBUCK_SHIFT;   // 391

    char* w = (char*)d_ws;
    size_t off = 0;
    auto alloc = [&](size_t b) { size_t o = off; off = (off + b + 255) & ~(size_t)255; return o; };
    float*        x1      = (float*)(w + alloc((size_t)n * 32 * 4));
    float*        x2      = (float*)(w + alloc((size_t)n * 32 * 4));
    unsigned int* h2a     = (unsigned int*)(w + alloc((size_t)n * 16 * 4));
    unsigned int* h2b     = (unsigned int*)(w + alloc((size_t)n * 16 * 4));
    float*        asrcA   = (float*)(w + alloc((size_t)n * 4));
    float*        adstA   = (float*)(w + alloc((size_t)n * 4));
    float*        asrcB   = (float*)(w + alloc((size_t)n * 4));
    float*        adstB   = (float*)(w + alloc((size_t)n * 4));
    float*        v0      = (float*)(w + alloc((size_t)n * 4));
    float*        v1      = (float*)(w + alloc((size_t)n * 4));
    float*        v2      = (float*)(w + alloc((size_t)n * 4));
    uint2*        st      = (uint2*)(w + alloc((size_t)ep * 8));
    uint2*        rec     = (uint2*)(w + alloc((size_t)ep * 8));
    int*          rp      = (int*)(w + alloc((size_t)(n + 1) * 4));
    int*          bcnt    = (int*)(w + alloc(NBUCK_MAX * 4));
    int*          bbase   = (int*)(w + alloc((NBUCK_MAX + 1) * 4));
    int*          bcur    = (int*)(w + alloc(NBUCK_MAX * 4));
    float2*       partial = (float2*)(w + alloc((size_t)8192 * 8));
    float*        consts  = (float*)(w + alloc(256));
    int*          bounds  = (int*)(w + alloc(129 * 4));
    float*        wfbuf   = (float*)(w + alloc(320 * 4));

    hipMemsetAsync(bcnt, 0, NBUCK_MAX * 4, stream);

    int e4   = e >> 2;
    int nbCS = (e4 + 255) / 256;         // 1563
    int nbH  = (ep + 4095) / 4096;       // 416
    int nw   = nbCS * 4;
    int nbN  = (n + 7) / 8;              // 12500

    k_pre<<<nbCS + nbH + 1, 256, 0, stream>>>(
        (const float4*)ea, W_ee, b_ee, partial, ei1, bcnt, batch, bounds,
        W_ne, b_ne, Wl[0], wfbuf, n, e, ep, nbCS, nbH);
    k_hproj0<<<nbN, 256, 0, stream>>>(nf, wfbuf, asl[0], adl[0],
                                      h2a, asrcA, adstA, n);
    k_mid<<<2, 512, 0, stream>>>(Wel[0], ael[0], Wel[1], ael[1], Wel[2], ael[2],
                                 partial, nw, 1.0f / (float)e, consts,
                                 bcnt, bbase, bcur, nbuck, ep, rp, n);
    k_binB<<<nbH, 256, 0, stream>>>(ei0, ei1, ea, W_ee, b_ee, consts, bcur, st, e, ep);
    k_binC<<<nbuck, 512, 0, stream>>>(st, bbase, rp, rec, n);

    // layer 0: h2a/A -> x1, v0
    k_agg<true><<<nbN, 256, 0, stream>>>(rp, rec, asrcA, adstA, consts, h2a,
                                         bbl[0], x1, W_l3 + 0, v0, n, 0);
    k_hproj<<<nbN, 256, 0, stream>>>(x1, Wl[1], asl[1], adl[1], h2b, asrcB, adstB, n);
    // layer 1: h2b/B -> x2, v1
    k_agg<true><<<nbN, 256, 0, stream>>>(rp, rec, asrcB, adstB, consts, h2b,
                                         bbl[1], x2, W_l3 + 32, v1, n, 1);
    k_hproj<<<nbN, 256, 0, stream>>>(x2, Wl[2], asl[2], adl[2], h2a, asrcA, adstA, n);
    // layer 2: h2a/A -> v2 only (x3 never materialized)
    k_agg<false><<<nbN, 256, 0, stream>>>(rp, rec, asrcA, adstA, consts, h2a,
                                          bbl[2], nullptr, W_l3 + 64, v2, n, 2);
    k_dotv<<<128, 256, 0, stream>>>(v0, v1, v2, bounds, b_l3, (float*)d_out);
}

// Round 15
// 337.140 us; speedup vs baseline: 1.3056x; 1.0331x over previous
//
#include <hip/hip_runtime.h>
#include <hip/hip_fp16.h>

// ---------------------------------------------------------------------------
// 3-layer GAT (heads=1) forward. N=100000, E=1600000, Ep=E+N, G=128,
// ND=16, ED=2, H=32.
// R15: traffic trims on the R14 structure.
//  - colsum fused into k_binB (ea read once there anyway); k_pre's 1563-block
//    colsum partition deleted. Self-loop recs carry a flag bit (bit23 of
//    rec.x); k_agg substitutes the per-layer loop logit consts[6+l] at use.
//    Consts reduce moved to an extra block of k_binC (post-binB).
//  - x1/x2 stored packed half2 (6.25MB vs 12.5); k_hproj reads packed.
//  - k_mid -> 1-block k_scan (bbase only).
// Carried: 32-lane agg body + fp16 h (R8), NT rec loads (R7), LDS bucket
// sort (R6), single-pass binC (R14), hproj0/Wf + v-scalar readout (R13/R14),
// no-atomics-in-hot-path rule (R2/R4/R9-R11), no in-agg GEMV (R13).
// ---------------------------------------------------------------------------

#define NBUCK_SHIFT 8
#define NBUCK_MAX 512
#define CAP 6144   // max staged edges per 256-node bucket (mean ~4350, max ~4650)
#define SLF_BIT 0x00800000u   // self-loop flag in rec.x (bit31 of sd >> 8)

// ---- fused preprocessing: [hist | (Wf + bounds)] --------------------------
__global__ void k_pre(const int* __restrict__ ei1, int* __restrict__ bucket_cnt,
                      const int* __restrict__ batch, int* __restrict__ bounds,
                      const float* __restrict__ Wne, const float* __restrict__ bne,
                      const float* __restrict__ W0, float* __restrict__ wf,
                      int n, int e, int ep, int nbH) {
    int b = blockIdx.x, t = threadIdx.x;
    if (b < nbH) {
        __shared__ int lh[NBUCK_MAX];
        lh[t] = 0; lh[t + 256] = 0;
        __syncthreads();
        int base = b * 4096;
#pragma unroll
        for (int i = 0; i < 16; ++i) {
            int gid = base + i * 256 + t;
            if (gid < ep) {
                int d = (gid < e) ? ei1[gid] : gid - e;
                atomicAdd(&lh[d >> NBUCK_SHIFT], 1);
            }
        }
        __syncthreads();
        if (lh[t]) atomicAdd(&bucket_cnt[t], lh[t]);
        if (lh[t + 256]) atomicAdd(&bucket_cnt[t + 256], lh[t + 256]);
        return;
    }
    // last block: fused layer-0 weights Wf = Wne@W0 (9x32), bf = bne@W0,
    // then graph bounds by binary search.
    for (int i = t; i < 288; i += 256) {
        int m = i >> 5, j = i & 31;
        float a = 0.f;
        for (int k = 0; k < 16; ++k) a += Wne[m * 16 + k] * W0[k * 32 + j];
        wf[i] = a;
    }
    if (t < 32) {
        float a = 0.f;
        for (int k = 0; k < 16; ++k) a += bne[k] * W0[k * 32 + t];
        wf[288 + t] = a;
    }
    for (int g = t; g <= 128; g += 256) {
        if (g == 128) { bounds[128] = n; continue; }
        int lo = 0, hi = n;
        while (lo < hi) {
            int mid = (lo + hi) >> 1;
            if (batch[mid] < g) lo = mid + 1; else hi = mid;
        }
        bounds[g] = lo;
    }
}

// Layer-0 projection straight from raw node features (x0 never exists):
// h0 = nf @ Wf + bf.  h stored packed half2.
__global__ void k_hproj0(const float* __restrict__ nf, const float* __restrict__ wf,
                         const float* __restrict__ as_, const float* __restrict__ ad_,
                         unsigned int* __restrict__ h2, float* __restrict__ asrc,
                         float* __restrict__ adst, int n) {
    int node = blockIdx.x * 8 + (threadIdx.x >> 5);
    int j = threadIdx.x & 31;
    if (node >= n) return;
    const float* xr = nf + node * 9;
    float acc = wf[288 + j];
#pragma unroll
    for (int m = 0; m < 9; ++m) acc += xr[m] * wf[m * 32 + j];
    float accp = __shfl_down(acc, 1, 32);
    if ((j & 1) == 0) {
        __half2 hh = __floats2half2_rn(acc, accp);
        h2[(size_t)node * 16 + (j >> 1)] = *reinterpret_cast<unsigned int*>(&hh);
    }
    float r1 = acc * as_[j], r2 = acc * ad_[j];
#pragma unroll
    for (int off = 16; off > 0; off >>= 1) {
        r1 += __shfl_xor(r1, off, 32);
        r2 += __shfl_xor(r2, off, 32);
    }
    if (j == 0) { asrc[node] = r1; adst[node] = r2; }
}

__device__ __forceinline__ float2 h2f2u(unsigned int hw) {
    __half2 hh = *reinterpret_cast<__half2*>(&hw);
    return make_float2(__low2float(hh), __high2float(hh));
}

// Mid-layer projection: h = x @ W, x packed half2 (16 words/node), W in LDS.
__global__ void k_hproj(const unsigned int* __restrict__ xh, const float* __restrict__ W,
                        const float* __restrict__ as_, const float* __restrict__ ad_,
                        unsigned int* __restrict__ h2, float* __restrict__ asrc,
                        float* __restrict__ adst, int n) {
    __shared__ float sW[1024];
    for (int i = threadIdx.x; i < 1024; i += 256) sW[i] = W[i];
    __syncthreads();
    int node = blockIdx.x * 8 + (threadIdx.x >> 5);
    int j = threadIdx.x & 31;
    if (node >= n) return;
    const unsigned int* xr = xh + (size_t)node * 16;
    float acc = 0.f;
#pragma unroll
    for (int w = 0; w < 16; ++w) {
        float2 f = h2f2u(xr[w]);
        acc += f.x * sW[(2 * w) * 32 + j] + f.y * sW[(2 * w + 1) * 32 + j];
    }
    float accp = __shfl_down(acc, 1, 32);
    if ((j & 1) == 0) {
        __half2 hh = __floats2half2_rn(acc, accp);
        h2[(size_t)node * 16 + (j >> 1)] = *reinterpret_cast<unsigned int*>(&hh);
    }
    float r1 = acc * as_[j], r2 = acc * ad_[j];
#pragma unroll
    for (int off = 16; off > 0; off >>= 1) {
        r1 += __shfl_xor(r1, off, 32);
        r2 += __shfl_xor(r2, off, 32);
    }
    if (j == 0) { asrc[node] = r1; adst[node] = r2; }
}

// Bucket-base scan (1 block).
__global__ void __launch_bounds__(512)
k_scan(const int* __restrict__ bucket_cnt, int* __restrict__ bucket_base,
       int* __restrict__ bcursor, int nbuck, int ep, int* __restrict__ rp, int n) {
    __shared__ int s[512];
    int t = threadIdx.x;
    int v = (t < nbuck) ? bucket_cnt[t] : 0;
    s[t] = v;
    __syncthreads();
    for (int o = 1; o < 512; o <<= 1) {
        int x = (t >= o) ? s[t - o] : 0;
        __syncthreads();
        s[t] += x;
        __syncthreads();
    }
    int ex = s[t] - v;
    if (t < nbuck) { bucket_base[t] = ex; bcursor[t] = ex; }
    if (t == 0) { bucket_base[nbuck] = ep; rp[n] = ep; }
}

// Phase B: stage edges grouped by bucket (8B uint2 {sd, half2}) AND compute
// ef column-sum partials (per-wave, unique slots, no atomics). Self-loop recs
// get flag bit31 in sd (no consts dependency here).
__global__ void k_binB(const int* __restrict__ ei0, const int* __restrict__ ei1,
                       const float* __restrict__ ea, const float* __restrict__ We,
                       const float* __restrict__ be, int* __restrict__ bcursor,
                       uint2* __restrict__ st, float2* __restrict__ partial,
                       int e, int ep) {
    __shared__ int lh[NBUCK_MAX], lcur[NBUCK_MAX];
    int t = threadIdx.x;
    lh[t] = 0; lh[t + 256] = 0;
    __syncthreads();
    int base = blockIdx.x * 4096;
    unsigned int sd[16], fh[16];
    int bk[16];
    float w00 = We[0], w10 = We[2], w20 = We[4];
    float w01 = We[1], w11 = We[3], w21 = We[5];
    float b0 = be[0], b1 = be[1];
    float cs0 = 0.f, cs1 = 0.f;
#pragma unroll
    for (int i = 0; i < 16; ++i) {
        int gid = base + i * 256 + t;
        bk[i] = -1;
        if (gid < ep) {
            int s, d;
            if (gid < e) {
                s = ei0[gid]; d = ei1[gid];
                const float* r = ea + (size_t)gid * 3;
                float a0 = r[0], a1 = r[1], a2 = r[2];
                float f0 = a0 * w00 + a1 * w10 + a2 * w20 + b0;
                float f1 = a0 * w01 + a1 * w11 + a2 * w21 + b1;
                cs0 += f0; cs1 += f1;
                sd[i] = ((unsigned int)s << NBUCK_SHIFT) | (unsigned int)(d & 255);
                __half2 hh = __floats2half2_rn(f0, f1);
                fh[i] = *reinterpret_cast<unsigned int*>(&hh);
            } else {
                s = d = gid - e;
                sd[i] = 0x80000000u | ((unsigned int)s << NBUCK_SHIFT)
                      | (unsigned int)(d & 255);
                fh[i] = 0;
            }
            bk[i] = d >> NBUCK_SHIFT;
            atomicAdd(&lh[bk[i]], 1);
        }
    }
    // per-wave colsum partial (real edges only)
#pragma unroll
    for (int off = 32; off > 0; off >>= 1) {
        cs0 += __shfl_xor(cs0, off, 64);
        cs1 += __shfl_xor(cs1, off, 64);
    }
    if ((t & 63) == 0)
        partial[(blockIdx.x << 2) + (t >> 6)] = make_float2(cs0, cs1);
    __syncthreads();
    if (lh[t] > 0) lcur[t] = atomicAdd(&bcursor[t], lh[t]);
    if (lh[t + 256] > 0) lcur[t + 256] = atomicAdd(&bcursor[t + 256], lh[t + 256]);
    __syncthreads();
#pragma unroll
    for (int i = 0; i < 16; ++i) {
        if (bk[i] >= 0) {
            int pos = atomicAdd(&lcur[bk[i]], 1);
            st[pos] = make_uint2(sd[i], fh[i]);
        }
    }
}

// Phase C: blocks [0,nbuck) sort one bucket each (single-pass, recs in
// registers); block nbuck reduces colsum partials -> consts
// ([0..5]=We@ae per layer, [6..8]=self-loop logit per layer).
__global__ void __launch_bounds__(512)
k_binC(const uint2* __restrict__ st, const int* __restrict__ bucket_base,
       int* __restrict__ rp, uint2* __restrict__ rec, int n, int nbuck,
       const float* __restrict__ We0, const float* __restrict__ ae0,
       const float* __restrict__ We1, const float* __restrict__ ae1,
       const float* __restrict__ We2, const float* __restrict__ ae2,
       const float2* __restrict__ partial, int nw, float einv,
       float* __restrict__ consts) {
    int k = blockIdx.x, t = threadIdx.x;
    if (k == nbuck) {
        __shared__ float r0[512], r1[512];
        float m0 = 0.f, m1 = 0.f;
        for (int i = t; i < nw; i += 512) {
            float2 v = partial[i];
            m0 += v.x; m1 += v.y;
        }
        r0[t] = m0; r1[t] = m1;
        __syncthreads();
        for (int o = 256; o > 0; o >>= 1) {
            if (t < o) { r0[t] += r0[t + o]; r1[t] += r1[t + o]; }
            __syncthreads();
        }
        if (t == 0) {
            float fm0 = r0[0] * einv, fm1 = r1[0] * einv;
            const float* We[3] = {We0, We1, We2};
            const float* ae[3] = {ae0, ae1, ae2};
            for (int l = 0; l < 3; ++l) {
                float c0 = 0.f, c1 = 0.f;
                for (int j = 0; j < 32; ++j) {
                    c0 += We[l][j] * ae[l][j];
                    c1 += We[l][32 + j] * ae[l][j];
                }
                consts[l * 2 + 0] = c0;
                consts[l * 2 + 1] = c1;
                consts[6 + l] = fm0 * c0 + fm1 * c1;
            }
        }
        return;
    }
    __shared__ int nh[256], ns[256];
    __shared__ uint2 rs[CAP];
    int s0 = bucket_base[k], s1 = bucket_base[k + 1];
    int cnt = s1 - s0;
    uint2 lv[12];
    if (t < 256) nh[t] = 0;
    __syncthreads();
#pragma unroll
    for (int u = 0; u < 12; ++u) {
        int i = s0 + u * 512 + t;
        if (i < s1) {
            uint2 v = st[i];
            lv[u] = v;
            atomicAdd(&nh[v.x & 255], 1);
        }
    }
    __syncthreads();
    if (t < 256) ns[t] = nh[t];
    __syncthreads();
    for (int o = 1; o < 256; o <<= 1) {
        int add = 0;
        if (t < 256 && t >= o) add = ns[t - o];
        __syncthreads();
        if (t < 256) ns[t] += add;
        __syncthreads();
    }
    int node0 = k << NBUCK_SHIFT;
    if (t < 256) {
        int startl = ns[t] - nh[t];
        if (node0 + t < n) rp[node0 + t] = s0 + startl;
        nh[t] = startl;
    }
    __syncthreads();
#pragma unroll
    for (int u = 0; u < 12; ++u) {
        int i = s0 + u * 512 + t;
        if (i < s1) {
            uint2 v = lv[u];
            int pos = atomicAdd(&nh[v.x & 255], 1);
            uint2 r = make_uint2(v.x >> NBUCK_SHIFT, v.y);  // flag lands at bit23
            if (pos < CAP) rs[pos] = r;
            else rec[s0 + pos] = r;      // overflow fallback (never in practice)
        }
    }
    __syncthreads();
    int m = cnt < CAP ? cnt : CAP;
    for (int i = t; i < m; i += 512)
        rec[s0 + i] = rs[i];
}

__device__ __forceinline__ float h2_get(const unsigned int* __restrict__ h2,
                                        int s, int word, bool hi) {
    unsigned int hw = h2[(size_t)s * 16 + word];
    __half2 hh = *reinterpret_cast<__half2*>(&hw);
    return hi ? __high2float(hh) : __low2float(hh);
}

// Fused edge-softmax + aggregation, 32-lane group per dst node (R8 body).
// rec.x: bit23 = self-loop flag (use consts[6+layer] logit), low bits = src.
// Epilogue: optional packed-half2 x store + per-node readout scalar (no atomics).
template <bool STORE_X>
__global__ void k_agg(const int* __restrict__ rp, const uint2* __restrict__ rec,
                      const float* __restrict__ asrc, const float* __restrict__ adst,
                      const float* __restrict__ consts, const unsigned int* __restrict__ h2,
                      const float* __restrict__ bb, unsigned int* __restrict__ xout,
                      const float* __restrict__ wl3, float* __restrict__ vout,
                      int n, int layer) {
    int node = blockIdx.x * 8 + (threadIdx.x >> 5);
    int j = threadIdx.x & 31;
    if (node >= n) return;
    float c0 = consts[layer * 2], c1 = consts[layer * 2 + 1];
    float loopc = consts[6 + layer];
    int r0 = rp[node], r1 = rp[node + 1];
    float adn = adst[node];
    int word = j >> 1;
    bool hi = (j & 1) != 0;
    float acc = 0.f, psum = 0.f;
    for (int c = r0; c < r1; c += 32) {
        int i = c + j;
        float pe = 0.f; int s = 0;
        if (i < r1) {
            unsigned long long rv = __builtin_nontemporal_load(
                reinterpret_cast<const unsigned long long*>(rec + i));
            unsigned int sx = (unsigned int)(rv & 0xffffffffull);
            s = (int)(sx & 0x7fffffu);
            unsigned int fv = (unsigned int)(rv >> 32);
            __half2 hh = *reinterpret_cast<__half2*>(&fv);
            float ae = (sx & SLF_BIT) ? loopc
                     : (__low2float(hh) * c0 + __high2float(hh) * c1);
            float lg = asrc[s] + adn + ae;
            lg = lg > 0.f ? lg : 0.2f * lg;
            pe = __expf(lg);
        }
        psum += pe;
        int cnt = min(32, r1 - c);
        int t = 0;
        for (; t + 8 <= cnt; t += 8) {
            int s0 = __shfl(s, t, 32),     s1 = __shfl(s, t + 1, 32);
            int s2 = __shfl(s, t + 2, 32), s3 = __shfl(s, t + 3, 32);
            int s4 = __shfl(s, t + 4, 32), s5 = __shfl(s, t + 5, 32);
            int s6 = __shfl(s, t + 6, 32), s7 = __shfl(s, t + 7, 32);
            float p0 = __shfl(pe, t, 32),     p1 = __shfl(pe, t + 1, 32);
            float p2 = __shfl(pe, t + 2, 32), p3 = __shfl(pe, t + 3, 32);
            float p4 = __shfl(pe, t + 4, 32), p5 = __shfl(pe, t + 5, 32);
            float p6 = __shfl(pe, t + 6, 32), p7 = __shfl(pe, t + 7, 32);
            float h0 = h2_get(h2, s0, word, hi);
            float h1 = h2_get(h2, s1, word, hi);
            float h2v = h2_get(h2, s2, word, hi);
            float h3 = h2_get(h2, s3, word, hi);
            float h4 = h2_get(h2, s4, word, hi);
            float h5 = h2_get(h2, s5, word, hi);
            float h6 = h2_get(h2, s6, word, hi);
            float h7 = h2_get(h2, s7, word, hi);
            acc += p0 * h0; acc += p1 * h1; acc += p2 * h2v; acc += p3 * h3;
            acc += p4 * h4; acc += p5 * h5; acc += p6 * h6; acc += p7 * h7;
        }
        for (; t + 4 <= cnt; t += 4) {
            int s0 = __shfl(s, t, 32),     s1 = __shfl(s, t + 1, 32);
            int s2 = __shfl(s, t + 2, 32), s3 = __shfl(s, t + 3, 32);
            float p0 = __shfl(pe, t, 32),     p1 = __shfl(pe, t + 1, 32);
            float p2 = __shfl(pe, t + 2, 32), p3 = __shfl(pe, t + 3, 32);
            float h0 = h2_get(h2, s0, word, hi);
            float h1 = h2_get(h2, s1, word, hi);
            float h2v = h2_get(h2, s2, word, hi);
            float h3 = h2_get(h2, s3, word, hi);
            acc += p0 * h0; acc += p1 * h1; acc += p2 * h2v; acc += p3 * h3;
        }
        for (; t < cnt; ++t) {
            int st2 = __shfl(s, t, 32);
            float pt = __shfl(pe, t, 32);
            acc += pt * h2_get(h2, st2, word, hi);
        }
    }
#pragma unroll
    for (int off = 16; off > 0; off >>= 1) psum += __shfl_xor(psum, off, 32);
    float res = acc / (psum + 1e-16f) + bb[j];
    if (STORE_X) {
        float resp = __shfl_down(res, 1, 32);
        if ((j & 1) == 0) {
            __half2 hh = __floats2half2_rn(res, resp);
            xout[(size_t)node * 16 + (j >> 1)] = *reinterpret_cast<unsigned int*>(&hh);
        }
    }
    float v = res * wl3[j];
#pragma unroll
    for (int off = 16; off > 0; off >>= 1) v += __shfl_xor(v, off, 32);
    if (j == 0) vout[node] = v;
}

// Readout: one block per graph, sums the three per-node scalars. 1.2MB total.
__global__ void k_dotv(const float* __restrict__ v0, const float* __restrict__ v1,
                       const float* __restrict__ v2, const int* __restrict__ bounds,
                       const float* __restrict__ bl3, float* __restrict__ out) {
    __shared__ float red[256];
    int g = blockIdx.x, t = threadIdx.x;
    int s0 = bounds[g], s1 = bounds[g + 1];
    float acc = 0.f;
    for (int i = s0 + t; i < s1; i += 256) acc += v0[i] + v1[i] + v2[i];
    red[t] = acc;
    __syncthreads();
    for (int o = 128; o > 0; o >>= 1) {
        if (t < o) red[t] += red[t + o];
        __syncthreads();
    }
    if (t == 0) {
        float c = (float)(s1 - s0);
        if (c < 1.f) c = 1.f;
        out[g] = red[0] / c + bl3[0];
    }
}

extern "C" void kernel_launch(void* const* d_in, const int* in_sizes, int n_in,
                              void* d_out, int out_size, void* d_ws, size_t ws_size,
                              hipStream_t stream) {
    (void)n_in; (void)out_size; (void)ws_size;
    const float* nf    = (const float*)d_in[0];
    const int*   ei    = (const int*)d_in[1];
    const float* ea    = (const float*)d_in[2];
    const int*   batch = (const int*)d_in[3];
    const float* W_ne  = (const float*)d_in[4];
    const float* b_ne  = (const float*)d_in[5];
    const float* W_ee  = (const float*)d_in[6];
    const float* b_ee  = (const float*)d_in[7];
    const float* W_l3  = (const float*)d_in[8];
    const float* b_l3  = (const float*)d_in[9];
    const float *Wl[3], *asl[3], *adl[3], *Wel[3], *ael[3], *bbl[3];
    for (int l = 0; l < 3; ++l) {
        Wl[l]  = (const float*)d_in[10 + 6 * l];
        asl[l] = (const float*)d_in[11 + 6 * l];
        adl[l] = (const float*)d_in[12 + 6 * l];
        Wel[l] = (const float*)d_in[13 + 6 * l];
        ael[l] = (const float*)d_in[14 + 6 * l];
        bbl[l] = (const float*)d_in[15 + 6 * l];
    }

    const int n  = in_sizes[3];        // 100000
    const int e  = in_sizes[2] / 3;    // 1600000
    const int ep = e + n;
    const int* ei0 = ei;
    const int* ei1 = ei + e;
    const int nbuck = (n + 255) >> NBUCK_SHIFT;   // 391

    char* w = (char*)d_ws;
    size_t off = 0;
    auto alloc = [&](size_t b) { size_t o = off; off = (off + b + 255) & ~(size_t)255; return o; };
    unsigned int* x1h     = (unsigned int*)(w + alloc((size_t)n * 16 * 4));
    unsigned int* x2h     = (unsigned int*)(w + alloc((size_t)n * 16 * 4));
    unsigned int* h2a     = (unsigned int*)(w + alloc((size_t)n * 16 * 4));
    unsigned int* h2b     = (unsigned int*)(w + alloc((size_t)n * 16 * 4));
    float*        asrcA   = (float*)(w + alloc((size_t)n * 4));
    float*        adstA   = (float*)(w + alloc((size_t)n * 4));
    float*        asrcB   = (float*)(w + alloc((size_t)n * 4));
    float*        adstB   = (float*)(w + alloc((size_t)n * 4));
    float*        v0      = (float*)(w + alloc((size_t)n * 4));
    float*        v1      = (float*)(w + alloc((size_t)n * 4));
    float*        v2      = (float*)(w + alloc((size_t)n * 4));
    uint2*        st      = (uint2*)(w + alloc((size_t)ep * 8));
    uint2*        rec     = (uint2*)(w + alloc((size_t)ep * 8));
    int*          rp      = (int*)(w + alloc((size_t)(n + 1) * 4));
    int*          bcnt    = (int*)(w + alloc(NBUCK_MAX * 4));
    int*          bbase   = (int*)(w + alloc((NBUCK_MAX + 1) * 4));
    int*          bcur    = (int*)(w + alloc(NBUCK_MAX * 4));
    float2*       partial = (float2*)(w + alloc((size_t)8192 * 8));
    float*        consts  = (float*)(w + alloc(256));
    int*          bounds  = (int*)(w + alloc(129 * 4));
    float*        wfbuf   = (float*)(w + alloc(320 * 4));

    hipMemsetAsync(bcnt, 0, NBUCK_MAX * 4, stream);

    int nbH = (ep + 4095) / 4096;        // 416
    int nw  = nbH * 4;                   // colsum partial slots (from binB)
    int nbN = (n + 7) / 8;               // 12500

    k_pre<<<nbH + 1, 256, 0, stream>>>(ei1, bcnt, batch, bounds,
                                       W_ne, b_ne, Wl[0], wfbuf, n, e, ep, nbH);
    k_hproj0<<<nbN, 256, 0, stream>>>(nf, wfbuf, asl[0], adl[0],
                                      h2a, asrcA, adstA, n);
    k_scan<<<1, 512, 0, stream>>>(bcnt, bbase, bcur, nbuck, ep, rp, n);
    k_binB<<<nbH, 256, 0, stream>>>(ei0, ei1, ea, W_ee, b_ee, bcur, st,
                                    partial, e, ep);
    k_binC<<<nbuck + 1, 512, 0, stream>>>(st, bbase, rp, rec, n, nbuck,
                                          Wel[0], ael[0], Wel[1], ael[1],
                                          Wel[2], ael[2], partial, nw,
                                          1.0f / (float)e, consts);

    // layer 0: h2a/A -> x1h, v0
    k_agg<true><<<nbN, 256, 0, stream>>>(rp, rec, asrcA, adstA, consts, h2a,
                                         bbl[0], x1h, W_l3 + 0, v0, n, 0);
    k_hproj<<<nbN, 256, 0, stream>>>(x1h, Wl[1], asl[1], adl[1], h2b, asrcB, adstB, n);
    // layer 1: h2b/B -> x2h, v1
    k_agg<true><<<nbN, 256, 0, stream>>>(rp, rec, asrcB, adstB, consts, h2b,
                                         bbl[1], x2h, W_l3 + 32, v1, n, 1);
    k_hproj<<<nbN, 256, 0, stream>>>(x2h, Wl[2], asl[2], adl[2], h2a, asrcA, adstA, n);
    // layer 2: h2a/A -> v2 only
    k_agg<false><<<nbN, 256, 0, stream>>>(rp, rec, asrcA, adstA, consts, h2a,
                                          bbl[2], nullptr, W_l3 + 64, v2, n, 2);
    k_dotv<<<128, 256, 0, stream>>>(v0, v1, v2, bounds, b_l3, (float*)d_out);
}